// Round 4
// baseline (1802.889 us; speedup 1.0000x reference)
//
#include <hip/hip_runtime.h>
#include <stdint.h>

#define Bz 8
#define Tz 1024
#define Cz 768
#define NHz 12
#define HDz 64
#define Gz 4   // heads per chunk; att0(bf16 8MiB)+att2(fp32 16MiB) = 24MiB = d_out exactly

typedef unsigned short u16;
typedef __attribute__((ext_vector_type(8))) __bf16 bf16x8;
typedef __attribute__((ext_vector_type(4))) float f32x4;

__device__ __forceinline__ float bf2f(u16 b) {
    union { uint32_t u; float f; } c; c.u = ((uint32_t)b) << 16; return c.f;
}
__device__ __forceinline__ u16 f2bf(float f) {
    union { float f; uint32_t u; } c; c.f = f;
    uint32_t u = c.u;
    return (u16)((u + 0x7fffu + ((u >> 16) & 1u)) >> 16);
}

// ---------------------------------------------------------------------------
// C = alpha * (A . B^T) [+ bias_col]   MFMA 16x16x32 bf16 compute.
// A: [M,K] row-major (lda, elements), fp32 if AF32 else bf16. Same for B.
// Output fp32 if OUTF32 else bf16. bias is fp32.
// Batched over blockIdx.z with element strides sAz/sBz/sCz.
// Staging: register round-trip (global -> regs -> cvt bf16 -> LDS).
// ---------------------------------------------------------------------------
template<int BM, int BN, int WM, int WN, bool AF32, bool BF32, bool OUTF32, bool HASBIAS>
__global__ __launch_bounds__(WM * WN * 64)
void gemm_bt(const void* __restrict__ A, long long sAz, int lda,
             const void* __restrict__ Bp, long long sBz, int ldb,
             void* __restrict__ Cp, long long sCz, int ldc,
             const float* __restrict__ bias, int K, float alpha) {
    constexpr int NT = WM * WN * 64;
    constexpr int BK = 32;
    constexpr int AI = (BM * BK) / (NT * 8);
    constexpr int BI = (BN * BK) / (NT * 8);
    static_assert(AI >= 1 && (BM * BK) % (NT * 8) == 0, "A staging");
    static_assert(BI >= 1 && (BN * BK) % (NT * 8) == 0, "B staging");
    static_assert(BM == WM * 64 && BN == WN * 64, "wave tiling");

    __shared__ alignas(16) u16 As[BM * BK];
    __shared__ alignas(16) u16 Bs[BN * BK];

    const int z = blockIdx.z;
    const float* Agf = (const float*)A + (AF32 ? (long long)z * sAz : 0);
    const u16*   Agh = (const u16*)A + (AF32 ? 0 : (long long)z * sAz);
    const float* Bgf = (const float*)Bp + (BF32 ? (long long)z * sBz : 0);
    const u16*   Bgh = (const u16*)Bp + (BF32 ? 0 : (long long)z * sBz);

    const int tid = threadIdx.x;
    const int lane = tid & 63;
    const int w = tid >> 6;
    const int wm = w / WN;
    const int wn = w % WN;
    const int rowBase = blockIdx.y * BM;
    const int colBase = blockIdx.x * BN;
    const int koff = (lane >> 4) * 8;   // k-offset of this lane's 8 elements
    const int frow = lane & 15;         // m (or n) index within 16-tile

    f32x4 acc[4][4] = {};

    for (int k0 = 0; k0 < K; k0 += BK) {
        // global -> registers (convert fp32 -> bf16 if needed)
        bf16x8 ra[AI], rb[BI];
#pragma unroll
        for (int i = 0; i < AI; i++) {
            int e = (i * NT + tid) * 8;               // flat element in [BM][BK]
            long long off = (long long)(rowBase + (e >> 5)) * lda + k0 + (e & 31);
            if (AF32) {
                float4 lo = *(const float4*)(Agf + off);
                float4 hi = *(const float4*)(Agf + off + 4);
                union { u16 h[8]; bf16x8 v; } o;
                o.h[0] = f2bf(lo.x); o.h[1] = f2bf(lo.y); o.h[2] = f2bf(lo.z); o.h[3] = f2bf(lo.w);
                o.h[4] = f2bf(hi.x); o.h[5] = f2bf(hi.y); o.h[6] = f2bf(hi.z); o.h[7] = f2bf(hi.w);
                ra[i] = o.v;
            } else {
                ra[i] = *(const bf16x8*)(Agh + off);
            }
        }
#pragma unroll
        for (int i = 0; i < BI; i++) {
            int e = (i * NT + tid) * 8;
            long long off = (long long)(colBase + (e >> 5)) * ldb + k0 + (e & 31);
            if (BF32) {
                float4 lo = *(const float4*)(Bgf + off);
                float4 hi = *(const float4*)(Bgf + off + 4);
                union { u16 h[8]; bf16x8 v; } o;
                o.h[0] = f2bf(lo.x); o.h[1] = f2bf(lo.y); o.h[2] = f2bf(lo.z); o.h[3] = f2bf(lo.w);
                o.h[4] = f2bf(hi.x); o.h[5] = f2bf(hi.y); o.h[6] = f2bf(hi.z); o.h[7] = f2bf(hi.w);
                rb[i] = o.v;
            } else {
                rb[i] = *(const bf16x8*)(Bgh + off);
            }
        }
        __syncthreads();   // previous iteration's LDS reads complete
#pragma unroll
        for (int i = 0; i < AI; i++) {
            int e = (i * NT + tid) * 8;
            *(bf16x8*)&As[e] = ra[i];
        }
#pragma unroll
        for (int i = 0; i < BI; i++) {
            int e = (i * NT + tid) * 8;
            *(bf16x8*)&Bs[e] = rb[i];
        }
        __syncthreads();

        bf16x8 af[4], bfr[4];
#pragma unroll
        for (int mt = 0; mt < 4; mt++)
            af[mt] = *(const bf16x8*)&As[(wm * 64 + mt * 16 + frow) * BK + koff];
#pragma unroll
        for (int nt = 0; nt < 4; nt++)
            bfr[nt] = *(const bf16x8*)&Bs[(wn * 64 + nt * 16 + frow) * BK + koff];
#pragma unroll
        for (int mt = 0; mt < 4; mt++)
#pragma unroll
            for (int nt = 0; nt < 4; nt++)
                acc[mt][nt] = __builtin_amdgcn_mfma_f32_16x16x32_bf16(
                    af[mt], bfr[nt], acc[mt][nt], 0, 0, 0);
    }

    // Epilogue. D layout: col = lane&15, row = (lane>>4)*4 + reg  [m89-verified]
    const int r0 = rowBase + wm * 64;
    const int c0 = colBase + wn * 64;
    const int rl = (lane >> 4) * 4;
    const int cl = lane & 15;
#pragma unroll
    for (int mt = 0; mt < 4; mt++) {
#pragma unroll
        for (int nt = 0; nt < 4; nt++) {
#pragma unroll
            for (int r = 0; r < 4; r++) {
                int row = r0 + mt * 16 + rl + r;
                int col = c0 + nt * 16 + cl;
                float v = acc[mt][nt][r] * alpha;
                if (HASBIAS) v += bias[col];
                if (OUTF32)
                    ((float*)Cp)[(long long)z * sCz + (long long)row * ldc + col] = v;
                else
                    ((u16*)Cp)[(long long)z * sCz + (long long)row * ldc + col] = f2bf(v);
            }
        }
    }
}

// ---------------------------------------------------------------------------
// Transpose to bf16: in [rows,cols] (fp32 if INF32 else bf16) -> out [cols,rows] bf16.
// ---------------------------------------------------------------------------
template<bool INF32>
__global__ __launch_bounds__(256)
void transpose_to_bf16(const void* __restrict__ in, u16* __restrict__ out,
                       int rows, int cols) {
    __shared__ u16 tile[32][33];
    const int c0 = blockIdx.x * 32, r0 = blockIdx.y * 32;
    const int tx = threadIdx.x, ty = threadIdx.y;  // 32 x 8
#pragma unroll
    for (int i = 0; i < 32; i += 8) {
        long long off = (long long)(r0 + ty + i) * cols + c0 + tx;
        tile[ty + i][tx] = INF32 ? f2bf(((const float*)in)[off]) : ((const u16*)in)[off];
    }
    __syncthreads();
#pragma unroll
    for (int i = 0; i < 32; i += 8)
        out[(long long)(c0 + ty + i) * rows + r0 + tx] = tile[tx][ty + i];
}

// ---------------------------------------------------------------------------
// Causal-masked softmax over fp32 logits row -> bf16 probs (0 beyond diag).
// grid: (T, G); block 256, 4 elements/thread.
// ---------------------------------------------------------------------------
__global__ __launch_bounds__(256)
void softmax_causal(const float* __restrict__ att, u16* __restrict__ probs) {
    const int i = blockIdx.x;
    const int h = blockIdx.y;
    const float* arow = att + ((long long)h * Tz + i) * Tz;
    u16* prow = probs + ((long long)h * Tz + i) * Tz;
    const int tid = threadIdx.x;
    const int lane = tid & 63;
    const int w = tid >> 6;
    const int j0 = tid * 4;

    float4 v4 = ((const float4*)arow)[tid];
    float v[4] = {v4.x, v4.y, v4.z, v4.w};

    float m = -3.0e38f;
#pragma unroll
    for (int u = 0; u < 4; u++)
        if (j0 + u <= i) m = fmaxf(m, v[u]);
    for (int off = 32; off > 0; off >>= 1) m = fmaxf(m, __shfl_down(m, off));

    __shared__ float smax[4], ssum[4];
    if (lane == 0) smax[w] = m;
    __syncthreads();
    m = fmaxf(fmaxf(smax[0], smax[1]), fmaxf(smax[2], smax[3]));

    float e[4];
    float s = 0.f;
#pragma unroll
    for (int u = 0; u < 4; u++) {
        e[u] = (j0 + u <= i) ? expf(v[u] - m) : 0.f;
        s += e[u];
    }
    for (int off = 32; off > 0; off >>= 1) s += __shfl_down(s, off);
    if (lane == 0) ssum[w] = s;
    __syncthreads();
    s = ssum[0] + ssum[1] + ssum[2] + ssum[3];
    const float inv = 1.f / s;

    union { u16 h4[4]; uint2 v2; } o;
#pragma unroll
    for (int u = 0; u < 4; u++) o.h4[u] = f2bf(e[u] * inv);
    ((uint2*)prow)[tid] = o.v2;
}

// ---------------------------------------------------------------------------
extern "C" void kernel_launch(void* const* d_in, const int* in_sizes, int n_in,
                              void* d_out, int out_size, void* d_ws, size_t ws_size,
                              hipStream_t stream) {
    // Reference dtypes: ALL inputs float32; output float32. bf16 only internal.
    const float* x  = (const float*)d_in[0];
    const float* Wv = (const float*)d_in[1];
    const float* bv = (const float*)d_in[2];
    const float* Wl = (const float*)d_in[3];
    const float* Wc = (const float*)d_in[4];
    const float* bc = (const float*)d_in[5];
    const float* Wp = (const float*)d_in[6];
    const float* bp = (const float*)d_in[7];

    // workspace -- 17.5 MiB:
    //   vbf [B,T,C] bf16 12 MiB (v; overwritten in-place by y per head-chunk;
    //                            chunk c's 5a reads cols [256c,256c+256)
    //                            strictly before its 5d writes them)
    //   vTb [C,T]  bf16 1.5 MiB (per-batch transpose of v[b])
    //   WlT [T,T]  bf16  2 MiB
    //   Wcl [T,T]  bf16  2 MiB
    // att chunk scratch lives in d_out (fp32 out = 24 MiB; step 6 overwrites):
    //   att0 [G,T,T] bf16 8 MiB + att2 [G,T,T] fp32 16 MiB = 24 MiB exact.
    u16* ws   = (u16*)d_ws;
    u16* vbf  = ws;
    u16* vTb  = vbf + (size_t)Bz * Tz * Cz;
    u16* WlT  = vTb + (size_t)Cz * Tz;
    u16* Wcl  = WlT + (size_t)Tz * Tz;
    u16* att0 = (u16*)d_out;                              // [G,T,T] bf16
    float* att2 = (float*)(att0 + (size_t)Gz * Tz * Tz);  // [G,T,T] fp32

    // 1) WlT = Wl^T  (fp32 -> bf16)
    transpose_to_bf16<true><<<dim3(32, 32, 1), dim3(32, 8), 0, stream>>>(Wl, WlT, Tz, Tz);
    // 2) Wcl = Wc . WlT^T = Wc @ Wl  (A fp32, B bf16 -> bf16)
    gemm_bt<128, 128, 2, 2, true, false, false, false><<<dim3(8, 8, 1), 256, 0, stream>>>(
        Wc, 0, Tz, WlT, 0, Tz, Wcl, 0, Tz, nullptr, Tz, 1.f);
    // 3) v = x . Wv^T + bv  (A fp32, B fp32 -> bf16)
    gemm_bt<128, 128, 2, 2, true, true, false, true><<<dim3(Cz / 128, (Bz * Tz) / 128, 1), 256, 0, stream>>>(
        x, 0, Cz, Wv, 0, Cz, vbf, 0, Cz, bv, Cz, 1.f);

    for (int b = 0; b < Bz; b++) {
        u16* vb = vbf + (size_t)b * Tz * Cz;
        // 4) vTb = v[b]^T  (bf16 [T,C] -> [C,T]) -- before any in-place y writes
        transpose_to_bf16<false><<<dim3(Cz / 32, Tz / 32, 1), dim3(32, 8), 0, stream>>>(vb, vTb, Tz, Cz);

        for (int c = 0; c < NHz / Gz; c++) {
            const int h0 = c * Gz;   // first head of chunk
            // 5a) att0[z] = (vh . vh^T) / sqrt(HD), heads h0..h0+G-1, K=64
            gemm_bt<128, 128, 2, 2, false, false, false, false><<<dim3(8, 8, Gz), 256, 0, stream>>>(
                vb + (size_t)h0 * HDz, HDz, Cz,
                vb + (size_t)h0 * HDz, HDz, Cz,
                att0, (long long)Tz * Tz, Tz, nullptr, HDz, 0.125f);
            // 5b) att2[z] = att0[z] . Wcl^T + bc   (bf16 x bf16 -> fp32 logits)
            gemm_bt<128, 128, 2, 2, false, false, true, true><<<dim3(8, 8, Gz), 256, 0, stream>>>(
                att0, (long long)Tz * Tz, Tz, Wcl, 0, Tz,
                att2, (long long)Tz * Tz, Tz, bc, Tz, 1.f);
            // 5c) causal softmax -> bf16 probs (overwrite att0)
            softmax_causal<<<dim3(Tz, Gz), 256, 0, stream>>>(att2, att0);
            // 5d) y cols [h0*64, (h0+G)*64) = P[z] . vh  -> in-place into vbf
            gemm_bt<128, 64, 2, 1, false, false, false, false><<<dim3(1, 8, Gz), 128, 0, stream>>>(
                att0, (long long)Tz * Tz, Tz,
                vTb + (size_t)h0 * HDz * Tz, (long long)HDz * Tz, Tz,
                vb + (size_t)h0 * HDz, HDz, Cz, nullptr, Tz, 1.f);
        }
    }

    // 6) out = y . Wp^T + bp  (A bf16, B fp32 -> fp32 d_out; att scratch dead)
    gemm_bt<128, 128, 2, 2, false, true, true, true><<<dim3(Cz / 128, (Bz * Tz) / 128, 1), 256, 0, stream>>>(
        vbf, 0, Cz, Wp, 0, Cz, (float*)d_out, 0, Cz, bp, Cz, 1.f);
}

// Round 5
// 918.105 us; speedup vs baseline: 1.9637x; 1.9637x over previous
//
#include <hip/hip_runtime.h>
#include <stdint.h>

#define Bz 8
#define Tz 1024
#define Cz 768
#define NHz 12
#define HDz 64

typedef unsigned short u16;
typedef __attribute__((ext_vector_type(8))) __bf16 bf16x8;
typedef __attribute__((ext_vector_type(4))) float f32x4;

__device__ __forceinline__ u16 f2bf(float f) {
    union { float f; uint32_t u; } c; c.f = f;
    uint32_t u = c.u;
    return (u16)((u + 0x7fffu + ((u >> 16) & 1u)) >> 16);
}

// ---------------------------------------------------------------------------
// C = alpha * (A . B^T) [+ bias_col]   MFMA 16x16x32 bf16 compute.
// A: [M,K] row-major (lda, elements), fp32 if AF32 else bf16. Same for B.
// Output fp32 if OUTF32 else bf16. bias is fp32.
// Batched over blockIdx.z with element strides sAz/sBz/sCz.
// Staging: bf16 operands use global_load_lds width=16 (async, m97 idiom;
// packed LDS, lane-contiguous so wave-uniform-base constraint holds);
// fp32 operands use register round-trip with fp32->bf16 convert.
// ---------------------------------------------------------------------------
template<int BM, int BN, int WM, int WN, bool AF32, bool BF32, bool OUTF32, bool HASBIAS>
__global__ __launch_bounds__(WM * WN * 64)
void gemm_bt(const void* __restrict__ A, long long sAz, int lda,
             const void* __restrict__ Bp, long long sBz, int ldb,
             void* __restrict__ Cp, long long sCz, int ldc,
             const float* __restrict__ bias, int K, float alpha) {
    constexpr int NT = WM * WN * 64;
    constexpr int BK = 32;
    constexpr int AI = (BM * BK) / (NT * 8);
    constexpr int BI = (BN * BK) / (NT * 8);
    static_assert(AI >= 1 && (BM * BK) % (NT * 8) == 0, "A staging");
    static_assert(BI >= 1 && (BN * BK) % (NT * 8) == 0, "B staging");
    static_assert(BM == WM * 64 && BN == WN * 64, "wave tiling");

    __shared__ alignas(16) u16 As[BM * BK];
    __shared__ alignas(16) u16 Bs[BN * BK];

    const int z = blockIdx.z;
    const float* Agf = (const float*)A + (AF32 ? (long long)z * sAz : 0);
    const u16*   Agh = (const u16*)A + (AF32 ? 0 : (long long)z * sAz);
    const float* Bgf = (const float*)Bp + (BF32 ? (long long)z * sBz : 0);
    const u16*   Bgh = (const u16*)Bp + (BF32 ? 0 : (long long)z * sBz);

    const int tid = threadIdx.x;
    const int lane = tid & 63;
    const int w = tid >> 6;
    const int wm = w / WN;
    const int wn = w % WN;
    const int rowBase = blockIdx.y * BM;
    const int colBase = blockIdx.x * BN;
    const int koff = (lane >> 4) * 8;   // k-offset of this lane's 8 elements
    const int frow = lane & 15;         // m (or n) index within 16-tile

    f32x4 acc[4][4] = {};

    for (int k0 = 0; k0 < K; k0 += BK) {
        // fp32 operands: global -> regs (+cvt) before the barrier
        bf16x8 ra[AI], rb[BI];
        if constexpr (AF32) {
#pragma unroll
            for (int i = 0; i < AI; i++) {
                int e = (i * NT + tid) * 8;
                long long off = (long long)(rowBase + (e >> 5)) * lda + k0 + (e & 31);
                float4 lo = *(const float4*)(Agf + off);
                float4 hi = *(const float4*)(Agf + off + 4);
                union { u16 h[8]; bf16x8 v; } o;
                o.h[0] = f2bf(lo.x); o.h[1] = f2bf(lo.y); o.h[2] = f2bf(lo.z); o.h[3] = f2bf(lo.w);
                o.h[4] = f2bf(hi.x); o.h[5] = f2bf(hi.y); o.h[6] = f2bf(hi.z); o.h[7] = f2bf(hi.w);
                ra[i] = o.v;
            }
        }
        if constexpr (BF32) {
#pragma unroll
            for (int i = 0; i < BI; i++) {
                int e = (i * NT + tid) * 8;
                long long off = (long long)(colBase + (e >> 5)) * ldb + k0 + (e & 31);
                float4 lo = *(const float4*)(Bgf + off);
                float4 hi = *(const float4*)(Bgf + off + 4);
                union { u16 h[8]; bf16x8 v; } o;
                o.h[0] = f2bf(lo.x); o.h[1] = f2bf(lo.y); o.h[2] = f2bf(lo.z); o.h[3] = f2bf(lo.w);
                o.h[4] = f2bf(hi.x); o.h[5] = f2bf(hi.y); o.h[6] = f2bf(hi.z); o.h[7] = f2bf(hi.w);
                rb[i] = o.v;
            }
        }
        __syncthreads();   // previous iteration's LDS reads complete
        if constexpr (AF32) {
#pragma unroll
            for (int i = 0; i < AI; i++) {
                int e = (i * NT + tid) * 8;
                *(bf16x8*)&As[e] = ra[i];
            }
        } else {
#pragma unroll
            for (int i = 0; i < AI; i++) {
                int e = (i * NT + tid) * 8;
                const u16* g = Agh + (long long)(rowBase + (e >> 5)) * lda + k0 + (e & 31);
                __builtin_amdgcn_global_load_lds(
                    (const __attribute__((address_space(1))) uint32_t*)g,
                    (__attribute__((address_space(3))) uint32_t*)(As + e), 16, 0, 0);
            }
        }
        if constexpr (BF32) {
#pragma unroll
            for (int i = 0; i < BI; i++) {
                int e = (i * NT + tid) * 8;
                *(bf16x8*)&Bs[e] = rb[i];
            }
        } else {
#pragma unroll
            for (int i = 0; i < BI; i++) {
                int e = (i * NT + tid) * 8;
                const u16* g = Bgh + (long long)(colBase + (e >> 5)) * ldb + k0 + (e & 31);
                __builtin_amdgcn_global_load_lds(
                    (const __attribute__((address_space(1))) uint32_t*)g,
                    (__attribute__((address_space(3))) uint32_t*)(Bs + e), 16, 0, 0);
            }
        }
        __syncthreads();   // compiler drains vmcnt(0)+lgkmcnt before barrier

        bf16x8 af[4], bfr[4];
#pragma unroll
        for (int mt = 0; mt < 4; mt++)
            af[mt] = *(const bf16x8*)&As[(wm * 64 + mt * 16 + frow) * BK + koff];
#pragma unroll
        for (int nt = 0; nt < 4; nt++)
            bfr[nt] = *(const bf16x8*)&Bs[(wn * 64 + nt * 16 + frow) * BK + koff];
#pragma unroll
        for (int mt = 0; mt < 4; mt++)
#pragma unroll
            for (int nt = 0; nt < 4; nt++)
                acc[mt][nt] = __builtin_amdgcn_mfma_f32_16x16x32_bf16(
                    af[mt], bfr[nt], acc[mt][nt], 0, 0, 0);
    }

    // Epilogue. D layout: col = lane&15, row = (lane>>4)*4 + reg  [m89-verified]
    const int r0 = rowBase + wm * 64;
    const int c0 = colBase + wn * 64;
    const int rl = (lane >> 4) * 4;
    const int cl = lane & 15;
#pragma unroll
    for (int mt = 0; mt < 4; mt++) {
#pragma unroll
        for (int nt = 0; nt < 4; nt++) {
#pragma unroll
            for (int r = 0; r < 4; r++) {
                int row = r0 + mt * 16 + rl + r;
                int col = c0 + nt * 16 + cl;
                float v = acc[mt][nt][r] * alpha;
                if (HASBIAS) v += bias[col];
                if (OUTF32)
                    ((float*)Cp)[(long long)z * sCz + (long long)row * ldc + col] = v;
                else
                    ((u16*)Cp)[(long long)z * sCz + (long long)row * ldc + col] = f2bf(v);
            }
        }
    }
}

// ---------------------------------------------------------------------------
// Transpose to bf16: in [rows,cols] (fp32 if INF32 else bf16) -> out
// [cols,rows] bf16. Batched over z with element strides.
// ---------------------------------------------------------------------------
template<bool INF32>
__global__ __launch_bounds__(256)
void transpose_to_bf16(const void* __restrict__ in, u16* __restrict__ out,
                       int rows, int cols, long long sInZ, long long sOutZ) {
    __shared__ u16 tile[32][33];
    const int z = blockIdx.z;
    const int c0 = blockIdx.x * 32, r0 = blockIdx.y * 32;
    const int tx = threadIdx.x, ty = threadIdx.y;  // 32 x 8
#pragma unroll
    for (int i = 0; i < 32; i += 8) {
        long long off = (long long)z * sInZ + (long long)(r0 + ty + i) * cols + c0 + tx;
        tile[ty + i][tx] = INF32 ? f2bf(((const float*)in)[off]) : ((const u16*)in)[off];
    }
    __syncthreads();
#pragma unroll
    for (int i = 0; i < 32; i += 8)
        out[(long long)z * sOutZ + (long long)(c0 + ty + i) * rows + r0 + tx] = tile[tx][ty + i];
}

// ---------------------------------------------------------------------------
// Causal-masked softmax over fp32 logits row -> bf16 probs (0 beyond diag).
// grid: (T, NH); block 256, 4 elements/thread.
// ---------------------------------------------------------------------------
__global__ __launch_bounds__(256)
void softmax_causal(const float* __restrict__ att, u16* __restrict__ probs) {
    const int i = blockIdx.x;
    const int h = blockIdx.y;
    const float* arow = att + ((long long)h * Tz + i) * Tz;
    u16* prow = probs + ((long long)h * Tz + i) * Tz;
    const int tid = threadIdx.x;
    const int lane = tid & 63;
    const int w = tid >> 6;
    const int j0 = tid * 4;

    float4 v4 = ((const float4*)arow)[tid];
    float v[4] = {v4.x, v4.y, v4.z, v4.w};

    float m = -3.0e38f;
#pragma unroll
    for (int u = 0; u < 4; u++)
        if (j0 + u <= i) m = fmaxf(m, v[u]);
    for (int off = 32; off > 0; off >>= 1) m = fmaxf(m, __shfl_down(m, off));

    __shared__ float smax[4], ssum[4];
    if (lane == 0) smax[w] = m;
    __syncthreads();
    m = fmaxf(fmaxf(smax[0], smax[1]), fmaxf(smax[2], smax[3]));

    float e[4];
    float s = 0.f;
#pragma unroll
    for (int u = 0; u < 4; u++) {
        e[u] = (j0 + u <= i) ? expf(v[u] - m) : 0.f;
        s += e[u];
    }
    for (int off = 32; off > 0; off >>= 1) s += __shfl_down(s, off);
    if (lane == 0) ssum[w] = s;
    __syncthreads();
    s = ssum[0] + ssum[1] + ssum[2] + ssum[3];
    const float inv = 1.f / s;

    union { u16 h4[4]; uint2 v2; } o;
#pragma unroll
    for (int u = 0; u < 4; u++) o.h4[u] = f2bf(e[u] * inv);
    ((uint2*)prow)[tid] = o.v2;
}

// ---------------------------------------------------------------------------
extern "C" void kernel_launch(void* const* d_in, const int* in_sizes, int n_in,
                              void* d_out, int out_size, void* d_ws, size_t ws_size,
                              hipStream_t stream) {
    // Reference dtypes: ALL inputs float32; output float32. bf16 internal.
    const float* x  = (const float*)d_in[0];
    const float* Wv = (const float*)d_in[1];
    const float* bv = (const float*)d_in[2];
    const float* Wl = (const float*)d_in[3];
    const float* Wc = (const float*)d_in[4];
    const float* bc = (const float*)d_in[5];
    const float* Wp = (const float*)d_in[6];
    const float* bp = (const float*)d_in[7];

    // workspace -- 100 MiB of the ~256 MiB available:
    //   vbf  [B,T,C]   bf16 12 MiB  (v; overwritten in-place by y: per batch,
    //                                5a reads vb strictly before 5d writes it)
    //   vT   [B,C,T]   bf16 12 MiB
    //   WlT  [T,T]     bf16  2 MiB
    //   Wcl  [T,T]     bf16  2 MiB
    //   att0 [NH,T,T]  bf16 24 MiB  (per-batch logits, then probs)
    //   att2 [NH,T,T]  fp32 48 MiB  (per-batch fp32 logits)
    // Per-batch att working set ~77 MiB < 256 MiB L3 -> att round-trips
    // should be largely Infinity-Cache-absorbed.
    u16* ws   = (u16*)d_ws;
    u16* vbf  = ws;
    u16* vT   = vbf + (size_t)Bz * Tz * Cz;
    u16* WlT  = vT  + (size_t)Bz * Tz * Cz;
    u16* Wcl  = WlT + (size_t)Tz * Tz;
    u16* att0 = Wcl + (size_t)Tz * Tz;                     // [NH,T,T] bf16
    float* att2 = (float*)(att0 + (size_t)NHz * Tz * Tz);  // [NH,T,T] fp32

    // 1) WlT = Wl^T  (fp32 -> bf16)
    transpose_to_bf16<true><<<dim3(32, 32, 1), dim3(32, 8), 0, stream>>>(Wl, WlT, Tz, Tz, 0, 0);
    // 2) Wcl = Wc . WlT^T = Wc @ Wl  (A fp32 reg-staged, B bf16 async)
    gemm_bt<128, 128, 2, 2, true, false, false, false><<<dim3(8, 8, 1), 256, 0, stream>>>(
        Wc, 0, Tz, WlT, 0, Tz, Wcl, 0, Tz, nullptr, Tz, 1.f);
    // 3) v = x . Wv^T + bv  (both fp32 reg-staged -> bf16)
    gemm_bt<128, 128, 2, 2, true, true, false, true><<<dim3(Cz / 128, (Bz * Tz) / 128, 1), 256, 0, stream>>>(
        x, 0, Cz, Wv, 0, Cz, vbf, 0, Cz, bv, Cz, 1.f);
    // 4) vT[b] = v[b]^T  for all batches (before any in-place y writes)
    transpose_to_bf16<false><<<dim3(Cz / 32, Tz / 32, Bz), dim3(32, 8), 0, stream>>>(
        vbf, vT, Tz, Cz, (long long)Tz * Cz, (long long)Cz * Tz);

    for (int b = 0; b < Bz; b++) {
        u16* vb  = vbf + (size_t)b * Tz * Cz;
        u16* vTb = vT  + (size_t)b * Cz * Tz;
        // 5a) att0[h] = (vh . vh^T) / sqrt(HD), all 12 heads, K=64  (async)
        gemm_bt<128, 128, 2, 2, false, false, false, false><<<dim3(8, 8, NHz), 256, 0, stream>>>(
            vb, HDz, Cz, vb, HDz, Cz,
            att0, (long long)Tz * Tz, Tz, nullptr, HDz, 0.125f);
        // 5b) att2[h] = att0[h] . Wcl^T + bc   (bf16 async -> fp32 logits)
        gemm_bt<128, 128, 2, 2, false, false, true, true><<<dim3(8, 8, NHz), 256, 0, stream>>>(
            att0, (long long)Tz * Tz, Tz, Wcl, 0, Tz,
            att2, (long long)Tz * Tz, Tz, bc, Tz, 1.f);
        // 5c) causal softmax -> bf16 probs (overwrite att0)
        softmax_causal<<<dim3(Tz, NHz), 256, 0, stream>>>(att2, att0);
        // 5d) y[:, h*64:(h+1)*64] = P[h] . vh  -> in-place into vb  (async)
        gemm_bt<128, 64, 2, 1, false, false, false, false><<<dim3(1, 8, NHz), 128, 0, stream>>>(
            att0, (long long)Tz * Tz, Tz,
            vTb, (long long)HDz * Tz, Tz,
            vb, HDz, Cz, nullptr, Tz, 1.f);
    }

    // 6) out = y . Wp^T + bp  (A bf16 async, B fp32 reg-staged -> fp32 d_out)
    gemm_bt<128, 128, 2, 2, false, true, true, true><<<dim3(Cz / 128, (Bz * Tz) / 128, 1), 256, 0, stream>>>(
        vbf, 0, Cz, Wp, 0, Cz, (float*)d_out, 0, Cz, bp, Cz, 1.f);
}

// Round 6
// 429.144 us; speedup vs baseline: 4.2011x; 2.1394x over previous
//
#include <hip/hip_runtime.h>
#include <stdint.h>

#define Bz 8
#define Tz 1024
#define Cz 768
#define NHz 12
#define HDz 64

typedef unsigned short u16;
typedef __attribute__((ext_vector_type(8))) __bf16 bf16x8;
typedef __attribute__((ext_vector_type(4))) float f32x4;

__device__ __forceinline__ float bf2f(u16 b) {
    union { uint32_t u; float f; } c; c.u = ((uint32_t)b) << 16; return c.f;
}
__device__ __forceinline__ u16 f2bf(float f) {
    union { float f; uint32_t u; } c; c.f = f;
    uint32_t u = c.u;
    return (u16)((u + 0x7fffu + ((u >> 16) & 1u)) >> 16);
}

// ---------------------------------------------------------------------------
// C = alpha * (A . B^T) [+ bias_col]   MFMA 16x16x32 bf16 compute.
// A: [M,K] row-major (lda, elements), fp32 if AF32 else bf16. Same for B.
// Output fp32 if OUTF32 else bf16. bias fp32.
// z-index split: zb = z/ZH, zh = z%ZH; operand offset = zb*s?b + zh*s?h.
// (ZH=1 -> plain batch; ZH=NH -> per-(batch,head) slices of a [B,T,C] tensor.)
// Staging: bf16 operands via global_load_lds width=16 (m97 idiom, packed LDS,
// lane-contiguous); fp32 operands via register round-trip + cvt.
// ---------------------------------------------------------------------------
template<int BM, int BN, int WM, int WN, int ZH, bool AF32, bool BF32, bool OUTF32, bool HASBIAS>
__global__ __launch_bounds__(WM * WN * 64)
void gemm_bt(const void* __restrict__ A, long long sAb, long long sAh, int lda,
             const void* __restrict__ Bp, long long sBb, long long sBh, int ldb,
             void* __restrict__ Cp, long long sCb, long long sCh, int ldc,
             const float* __restrict__ bias, int K, float alpha) {
    constexpr int NT = WM * WN * 64;
    constexpr int BK = 32;
    constexpr int AI = (BM * BK) / (NT * 8);
    constexpr int BI = (BN * BK) / (NT * 8);
    static_assert(AI >= 1 && (BM * BK) % (NT * 8) == 0, "A staging");
    static_assert(BI >= 1 && (BN * BK) % (NT * 8) == 0, "B staging");
    static_assert(BM == WM * 64 && BN == WN * 64, "wave tiling");

    __shared__ alignas(16) u16 As[BM * BK];
    __shared__ alignas(16) u16 Bs[BN * BK];

    const int z = blockIdx.z;
    const int zb = (ZH == 1) ? z : z / ZH;
    const int zh = (ZH == 1) ? 0 : z % ZH;
    const long long offA = (long long)zb * sAb + (long long)zh * sAh;
    const long long offB = (long long)zb * sBb + (long long)zh * sBh;
    const long long offC = (long long)zb * sCb + (long long)zh * sCh;

    const float* Agf = (const float*)A + (AF32 ? offA : 0);
    const u16*   Agh = (const u16*)A + (AF32 ? 0 : offA);
    const float* Bgf = (const float*)Bp + (BF32 ? offB : 0);
    const u16*   Bgh = (const u16*)Bp + (BF32 ? 0 : offB);

    const int tid = threadIdx.x;
    const int lane = tid & 63;
    const int w = tid >> 6;
    const int wm = w / WN;
    const int wn = w % WN;
    const int rowBase = blockIdx.y * BM;
    const int colBase = blockIdx.x * BN;
    const int koff = (lane >> 4) * 8;   // k-offset of this lane's 8 elements
    const int frow = lane & 15;         // m (or n) index within 16-tile

    f32x4 acc[4][4] = {};

    for (int k0 = 0; k0 < K; k0 += BK) {
        // fp32 operands: global -> regs (+cvt) before the barrier
        bf16x8 ra[AI], rb[BI];
        if constexpr (AF32) {
#pragma unroll
            for (int i = 0; i < AI; i++) {
                int e = (i * NT + tid) * 8;
                long long off = (long long)(rowBase + (e >> 5)) * lda + k0 + (e & 31);
                float4 lo = *(const float4*)(Agf + off);
                float4 hi = *(const float4*)(Agf + off + 4);
                union { u16 h[8]; bf16x8 v; } o;
                o.h[0] = f2bf(lo.x); o.h[1] = f2bf(lo.y); o.h[2] = f2bf(lo.z); o.h[3] = f2bf(lo.w);
                o.h[4] = f2bf(hi.x); o.h[5] = f2bf(hi.y); o.h[6] = f2bf(hi.z); o.h[7] = f2bf(hi.w);
                ra[i] = o.v;
            }
        }
        if constexpr (BF32) {
#pragma unroll
            for (int i = 0; i < BI; i++) {
                int e = (i * NT + tid) * 8;
                long long off = (long long)(colBase + (e >> 5)) * ldb + k0 + (e & 31);
                float4 lo = *(const float4*)(Bgf + off);
                float4 hi = *(const float4*)(Bgf + off + 4);
                union { u16 h[8]; bf16x8 v; } o;
                o.h[0] = f2bf(lo.x); o.h[1] = f2bf(lo.y); o.h[2] = f2bf(lo.z); o.h[3] = f2bf(lo.w);
                o.h[4] = f2bf(hi.x); o.h[5] = f2bf(hi.y); o.h[6] = f2bf(hi.z); o.h[7] = f2bf(hi.w);
                rb[i] = o.v;
            }
        }
        __syncthreads();   // previous iteration's LDS reads complete
        if constexpr (AF32) {
#pragma unroll
            for (int i = 0; i < AI; i++) {
                int e = (i * NT + tid) * 8;
                *(bf16x8*)&As[e] = ra[i];
            }
        } else {
#pragma unroll
            for (int i = 0; i < AI; i++) {
                int e = (i * NT + tid) * 8;
                const u16* g = Agh + (long long)(rowBase + (e >> 5)) * lda + k0 + (e & 31);
                __builtin_amdgcn_global_load_lds(
                    (const __attribute__((address_space(1))) uint32_t*)g,
                    (__attribute__((address_space(3))) uint32_t*)(As + e), 16, 0, 0);
            }
        }
        if constexpr (BF32) {
#pragma unroll
            for (int i = 0; i < BI; i++) {
                int e = (i * NT + tid) * 8;
                *(bf16x8*)&Bs[e] = rb[i];
            }
        } else {
#pragma unroll
            for (int i = 0; i < BI; i++) {
                int e = (i * NT + tid) * 8;
                const u16* g = Bgh + (long long)(colBase + (e >> 5)) * ldb + k0 + (e & 31);
                __builtin_amdgcn_global_load_lds(
                    (const __attribute__((address_space(1))) uint32_t*)g,
                    (__attribute__((address_space(3))) uint32_t*)(Bs + e), 16, 0, 0);
            }
        }
        __syncthreads();   // compiler drains vmcnt(0)+lgkmcnt before barrier

        bf16x8 af[4], bfr[4];
#pragma unroll
        for (int mt = 0; mt < 4; mt++)
            af[mt] = *(const bf16x8*)&As[(wm * 64 + mt * 16 + frow) * BK + koff];
#pragma unroll
        for (int nt = 0; nt < 4; nt++)
            bfr[nt] = *(const bf16x8*)&Bs[(wn * 64 + nt * 16 + frow) * BK + koff];
#pragma unroll
        for (int mt = 0; mt < 4; mt++)
#pragma unroll
            for (int nt = 0; nt < 4; nt++)
                acc[mt][nt] = __builtin_amdgcn_mfma_f32_16x16x32_bf16(
                    af[mt], bfr[nt], acc[mt][nt], 0, 0, 0);
    }

    // Epilogue. D layout: col = lane&15, row = (lane>>4)*4 + reg  [m89-verified]
    const int r0 = rowBase + wm * 64;
    const int c0 = colBase + wn * 64;
    const int rl = (lane >> 4) * 4;
    const int cl = lane & 15;
#pragma unroll
    for (int mt = 0; mt < 4; mt++) {
#pragma unroll
        for (int nt = 0; nt < 4; nt++) {
#pragma unroll
            for (int r = 0; r < 4; r++) {
                int row = r0 + mt * 16 + rl + r;
                int col = c0 + nt * 16 + cl;
                float v = acc[mt][nt][r] * alpha;
                if (HASBIAS) v += bias[col];
                if (OUTF32)
                    ((float*)Cp)[offC + (long long)row * ldc + col] = v;
                else
                    ((u16*)Cp)[offC + (long long)row * ldc + col] = f2bf(v);
            }
        }
    }
}

// ---------------------------------------------------------------------------
// Transpose to bf16: in [rows,cols] (fp32 if INF32 else bf16) -> out
// [cols,rows] bf16. Batched over z with element strides.
// ---------------------------------------------------------------------------
template<bool INF32>
__global__ __launch_bounds__(256)
void transpose_to_bf16(const void* __restrict__ in, u16* __restrict__ out,
                       int rows, int cols, long long sInZ, long long sOutZ) {
    __shared__ u16 tile[32][33];
    const int z = blockIdx.z;
    const int c0 = blockIdx.x * 32, r0 = blockIdx.y * 32;
    const int tx = threadIdx.x, ty = threadIdx.y;  // 32 x 8
#pragma unroll
    for (int i = 0; i < 32; i += 8) {
        long long off = (long long)z * sInZ + (long long)(r0 + ty + i) * cols + c0 + tx;
        tile[ty + i][tx] = INF32 ? f2bf(((const float*)in)[off]) : ((const u16*)in)[off];
    }
    __syncthreads();
#pragma unroll
    for (int i = 0; i < 32; i += 8)
        out[(long long)z * sOutZ + (long long)(c0 + ty + i) * rows + r0 + tx] = tile[tx][ty + i];
}

// ---------------------------------------------------------------------------
// Causal-masked softmax over bf16 logits row, IN-PLACE -> bf16 probs.
// grid: (T, B*NH); block 256, 4 elements/thread.
// ---------------------------------------------------------------------------
__global__ __launch_bounds__(256)
void softmax_causal_bf16(u16* __restrict__ att) {
    const int i = blockIdx.x;
    const long long z = blockIdx.y;
    u16* row = att + (z * Tz + i) * Tz;
    const int tid = threadIdx.x;
    const int lane = tid & 63;
    const int w = tid >> 6;
    const int j0 = tid * 4;

    union { u16 h4[4]; uint2 v2; } in;
    in.v2 = ((const uint2*)row)[tid];
    float v[4];
#pragma unroll
    for (int u = 0; u < 4; u++) v[u] = bf2f(in.h4[u]);

    float m = -3.0e38f;
#pragma unroll
    for (int u = 0; u < 4; u++)
        if (j0 + u <= i) m = fmaxf(m, v[u]);
    for (int off = 32; off > 0; off >>= 1) m = fmaxf(m, __shfl_down(m, off));

    __shared__ float smax[4], ssum[4];
    if (lane == 0) smax[w] = m;
    __syncthreads();
    m = fmaxf(fmaxf(smax[0], smax[1]), fmaxf(smax[2], smax[3]));

    float e[4];
    float s = 0.f;
#pragma unroll
    for (int u = 0; u < 4; u++) {
        e[u] = (j0 + u <= i) ? expf(v[u] - m) : 0.f;
        s += e[u];
    }
    for (int off = 32; off > 0; off >>= 1) s += __shfl_down(s, off);
    if (lane == 0) ssum[w] = s;
    __syncthreads();
    s = ssum[0] + ssum[1] + ssum[2] + ssum[3];
    const float inv = 1.f / s;

    union { u16 h4[4]; uint2 v2; } o;
#pragma unroll
    for (int u = 0; u < 4; u++) o.h4[u] = f2bf(e[u] * inv);
    ((uint2*)row)[tid] = o.v2;
}

// ---------------------------------------------------------------------------
extern "C" void kernel_launch(void* const* d_in, const int* in_sizes, int n_in,
                              void* d_out, int out_size, void* d_ws, size_t ws_size,
                              hipStream_t stream) {
    const float* x  = (const float*)d_in[0];
    const float* Wv = (const float*)d_in[1];
    const float* bv = (const float*)d_in[2];
    const float* Wl = (const float*)d_in[3];
    const float* Wc = (const float*)d_in[4];
    const float* bc = (const float*)d_in[5];
    const float* Wp = (const float*)d_in[6];
    const float* bp = (const float*)d_in[7];

    // Algebra: att2 = (vh vh^T/8) Wcl^T = vh (Wcl vh)^T / 8, Wcl = Wc@Wl.
    // U[b] = Wcl @ v[b] computes ALL head slices at once ([T,C]).
    // This cuts the dominant GEMM from 206 GF to 26 GF and kills att0.
    //
    // workspace -- 232 MiB of 256 MiB:
    //   vbf [B,T,C] bf16 12 MiB (v; later overwritten in-place by y)
    //   vT  [B,C,T] bf16 12 MiB
    //   WlT [T,T]   bf16  2 MiB
    //   Wcl [T,T]   bf16  2 MiB
    //   U   [B,T,C] bf16 12 MiB (Wcl @ v[b])
    //   att [B,NH,T,T] bf16 192 MiB (logits -> in-place softmax -> probs)
    u16* ws   = (u16*)d_ws;
    u16* vbf  = ws;
    u16* vT   = vbf + (size_t)Bz * Tz * Cz;
    u16* WlT  = vT  + (size_t)Bz * Tz * Cz;
    u16* Wcl  = WlT + (size_t)Tz * Tz;
    u16* U    = Wcl + (size_t)Tz * Tz;
    u16* att  = U   + (size_t)Bz * Tz * Cz;

    const long long sTC = (long long)Tz * Cz;
    const long long sCT = (long long)Cz * Tz;
    const long long sTT = (long long)Tz * Tz;

    // 1) WlT = Wl^T  (fp32 -> bf16)
    transpose_to_bf16<true><<<dim3(32, 32, 1), dim3(32, 8), 0, stream>>>(Wl, WlT, Tz, Tz, 0, 0);
    // 2) Wcl = Wc . WlT^T = Wc @ Wl
    gemm_bt<128, 128, 2, 2, 1, true, false, false, false><<<dim3(8, 8, 1), 256, 0, stream>>>(
        Wc, 0, 0, Tz, WlT, 0, 0, Tz, Wcl, 0, 0, Tz, nullptr, Tz, 1.f);
    // 3) v = x . Wv^T + bv
    gemm_bt<128, 128, 2, 2, 1, true, true, false, true><<<dim3(Cz / 128, (Bz * Tz) / 128, 1), 256, 0, stream>>>(
        x, 0, 0, Cz, Wv, 0, 0, Cz, vbf, 0, 0, Cz, bv, Cz, 1.f);
    // 4) vT[b] = v[b]^T
    transpose_to_bf16<false><<<dim3(Cz / 32, Tz / 32, Bz), dim3(32, 8), 0, stream>>>(
        vbf, vT, Tz, Cz, sTC, sCT);
    // 5) U[b] = Wcl . vT[b]^T = Wcl @ v[b]   [T,C], K=T
    gemm_bt<128, 128, 2, 2, 1, false, false, false, false><<<dim3(Cz / 128, Tz / 128, Bz), 256, 0, stream>>>(
        Wcl, 0, 0, Tz, vT, sCT, 0, Tz, U, sTC, 0, Cz, nullptr, Tz, 1.f);
    // 6) logits[b,h] = vh . Uh^T / 8 + bc   (K=64, bf16 out, all 96 slices)
    gemm_bt<128, 128, 2, 2, NHz, false, false, false, true><<<dim3(8, 8, Bz * NHz), 256, 0, stream>>>(
        vbf, sTC, HDz, Cz, U, sTC, HDz, Cz,
        att, (long long)NHz * sTT, sTT, Tz, bc, HDz, 0.125f);
    // 7) causal softmax in-place (bf16)
    softmax_causal_bf16<<<dim3(Tz, Bz * NHz), 256, 0, stream>>>(att);
    // 8) y[b][:, h*64:(h+1)*64] = P[b,h] . vh  -> in-place into vbf
    gemm_bt<128, 64, 2, 1, NHz, false, false, false, false><<<dim3(1, 8, Bz * NHz), 128, 0, stream>>>(
        att, (long long)NHz * sTT, sTT, Tz,
        vT, sCT, (long long)HDz * Tz, Tz,
        vbf, sTC, HDz, Cz, nullptr, Tz, 1.f);
    // 9) out = y . Wp^T + bp  (fp32 out)
    gemm_bt<128, 128, 2, 2, 1, false, true, true, true><<<dim3(Cz / 128, (Bz * Tz) / 128, 1), 256, 0, stream>>>(
        vbf, 0, 0, Cz, Wp, 0, 0, Cz, (float*)d_out, 0, 0, Cz, bp, Cz, 1.f);
}

// Round 7
// 339.261 us; speedup vs baseline: 5.3142x; 1.2649x over previous
//
#include <hip/hip_runtime.h>
#include <stdint.h>

#define Bz 8
#define Tz 1024
#define Cz 768
#define NHz 12
#define HDz 64

typedef unsigned short u16;
typedef __attribute__((ext_vector_type(8))) __bf16 bf16x8;
typedef __attribute__((ext_vector_type(4))) float f32x4;

__device__ __forceinline__ float bf2f(u16 b) {
    union { uint32_t u; float f; } c; c.u = ((uint32_t)b) << 16; return c.f;
}
__device__ __forceinline__ u16 f2bf(float f) {
    union { float f; uint32_t u; } c; c.f = f;
    uint32_t u = c.u;
    return (u16)((u + 0x7fffu + ((u >> 16) & 1u)) >> 16);
}

// ---------------------------------------------------------------------------
// fp32 -> bf16 elementwise convert (float4 / uint2 vectorized).
// ---------------------------------------------------------------------------
__global__ __launch_bounds__(256)
void cvt_f32_bf16(const float* __restrict__ in, u16* __restrict__ out, int n4) {
    int i = blockIdx.x * 256 + threadIdx.x;
    if (i < n4) {
        float4 v = ((const float4*)in)[i];
        union { u16 h[4]; uint2 u; } o;
        o.h[0] = f2bf(v.x); o.h[1] = f2bf(v.y); o.h[2] = f2bf(v.z); o.h[3] = f2bf(v.w);
        ((uint2*)out)[i] = o.u;
    }
}

// ---------------------------------------------------------------------------
// C = alpha * (A . B^T) [+ bias_col]   MFMA 16x16x32, all-bf16 operands.
// A: [M,K] bf16 row-major (lda), B: [N,K] bf16 row-major (ldb).
// Output fp32 if OUTF32 else bf16; bias fp32. Batched over blockIdx.z.
// bf16 staging via global_load_lds width=16 (m97 idiom, packed LDS).
// ---------------------------------------------------------------------------
template<int BM, int BN, int WM, int WN, bool OUTF32, bool HASBIAS>
__global__ __launch_bounds__(WM * WN * 64)
void gemm_bt(const u16* __restrict__ A, long long sAz, int lda,
             const u16* __restrict__ Bp, long long sBz, int ldb,
             void* __restrict__ Cp, long long sCz, int ldc,
             const float* __restrict__ bias, int K, float alpha) {
    constexpr int NT = WM * WN * 64;
    constexpr int BK = 32;
    constexpr int AI = (BM * BK) / (NT * 8);
    constexpr int BI = (BN * BK) / (NT * 8);
    static_assert(AI >= 1 && (BM * BK) % (NT * 8) == 0, "A staging");
    static_assert(BI >= 1 && (BN * BK) % (NT * 8) == 0, "B staging");
    static_assert(BM == WM * 64 && BN == WN * 64, "wave tiling");

    __shared__ alignas(16) u16 As[BM * BK];
    __shared__ alignas(16) u16 Bs[BN * BK];

    const int z = blockIdx.z;
    const u16* Ag = A + (long long)z * sAz;
    const u16* Bg = Bp + (long long)z * sBz;

    const int tid = threadIdx.x;
    const int lane = tid & 63;
    const int w = tid >> 6;
    const int wm = w / WN;
    const int wn = w % WN;
    const int rowBase = blockIdx.y * BM;
    const int colBase = blockIdx.x * BN;
    const int koff = (lane >> 4) * 8;
    const int frow = lane & 15;

    f32x4 acc[4][4] = {};

    for (int k0 = 0; k0 < K; k0 += BK) {
        __syncthreads();
#pragma unroll
        for (int i = 0; i < AI; i++) {
            int e = (i * NT + tid) * 8;
            const u16* g = Ag + (long long)(rowBase + (e >> 5)) * lda + k0 + (e & 31);
            __builtin_amdgcn_global_load_lds(
                (const __attribute__((address_space(1))) uint32_t*)g,
                (__attribute__((address_space(3))) uint32_t*)(As + e), 16, 0, 0);
        }
#pragma unroll
        for (int i = 0; i < BI; i++) {
            int e = (i * NT + tid) * 8;
            const u16* g = Bg + (long long)(colBase + (e >> 5)) * ldb + k0 + (e & 31);
            __builtin_amdgcn_global_load_lds(
                (const __attribute__((address_space(1))) uint32_t*)g,
                (__attribute__((address_space(3))) uint32_t*)(Bs + e), 16, 0, 0);
        }
        __syncthreads();

        bf16x8 af[4], bfr[4];
#pragma unroll
        for (int mt = 0; mt < 4; mt++)
            af[mt] = *(const bf16x8*)&As[(wm * 64 + mt * 16 + frow) * BK + koff];
#pragma unroll
        for (int nt = 0; nt < 4; nt++)
            bfr[nt] = *(const bf16x8*)&Bs[(wn * 64 + nt * 16 + frow) * BK + koff];
#pragma unroll
        for (int mt = 0; mt < 4; mt++)
#pragma unroll
            for (int nt = 0; nt < 4; nt++)
                acc[mt][nt] = __builtin_amdgcn_mfma_f32_16x16x32_bf16(
                    af[mt], bfr[nt], acc[mt][nt], 0, 0, 0);
    }

    const int r0 = rowBase + wm * 64;
    const int c0 = colBase + wn * 64;
    const int rl = (lane >> 4) * 4;
    const int cl = lane & 15;
#pragma unroll
    for (int mt = 0; mt < 4; mt++) {
#pragma unroll
        for (int nt = 0; nt < 4; nt++) {
#pragma unroll
            for (int r = 0; r < 4; r++) {
                int row = r0 + mt * 16 + rl + r;
                int col = c0 + nt * 16 + cl;
                float v = acc[mt][nt][r] * alpha;
                if (HASBIAS) v += bias[col];
                if (OUTF32)
                    ((float*)Cp)[(long long)z * sCz + (long long)row * ldc + col] = v;
                else
                    ((u16*)Cp)[(long long)z * sCz + (long long)row * ldc + col] = f2bf(v);
            }
        }
    }
}

// ---------------------------------------------------------------------------
// Transpose to bf16: in [rows,cols] (fp32 if INF32 else bf16) -> [cols,rows].
// ---------------------------------------------------------------------------
template<bool INF32>
__global__ __launch_bounds__(256)
void transpose_to_bf16(const void* __restrict__ in, u16* __restrict__ out,
                       int rows, int cols, long long sInZ, long long sOutZ) {
    __shared__ u16 tile[32][33];
    const int z = blockIdx.z;
    const int c0 = blockIdx.x * 32, r0 = blockIdx.y * 32;
    const int tx = threadIdx.x, ty = threadIdx.y;
#pragma unroll
    for (int i = 0; i < 32; i += 8) {
        long long off = (long long)z * sInZ + (long long)(r0 + ty + i) * cols + c0 + tx;
        tile[ty + i][tx] = INF32 ? f2bf(((const float*)in)[off]) : ((const u16*)in)[off];
    }
    __syncthreads();
#pragma unroll
    for (int i = 0; i < 32; i += 8)
        out[(long long)z * sOutZ + (long long)(c0 + ty + i) * rows + r0 + tx] = tile[tx][ty + i];
}

// ---------------------------------------------------------------------------
// Fused flash attention: logits = vq.Uk^T/8 + bc -> causal online softmax ->
// O = P.V. One block per (q-tile 128, head, batch); 4 waves, each owns 32
// q-rows (softmax reductions stay intra-wave: shfl_xor<16 preserves quad).
// In-place y into v is race-free: each block reads exactly the v region it
// writes (own q-rows x own head cols), reads precede writes in program order.
// ---------------------------------------------------------------------------
__global__ __launch_bounds__(256)
void flash_attn(const u16* __restrict__ v, const u16* __restrict__ U,
                const u16* __restrict__ vT, const float* __restrict__ bc,
                u16* __restrict__ y) {
    __shared__ alignas(16) u16 Us[128 * 64];    // keys x dims (packed)
    __shared__ alignas(16) u16 Vs[64 * 128];    // dims x keys (packed)
    __shared__ alignas(16) u16 Ps[128 * 136];   // q x keys, stride 136 (16B-aligned rows)
    __shared__ float bcs[Tz];

    const int qi = blockIdx.x, h = blockIdx.y, b = blockIdx.z;
    const int tid = threadIdx.x, lane = tid & 63, w = tid >> 6;
    const int quad = lane >> 4, cl = lane & 15;
    const int q0 = qi * 128;
    const int wrow = w * 32;

    for (int j = tid; j < Tz; j += 256) bcs[j] = bc[j];

    // resident A-fragments of vq (this block's own 128x64 slice)
    const u16* vq = v + ((long long)b * Tz + q0) * Cz + h * HDz;
    bf16x8 aS[2][2];
#pragma unroll
    for (int mt = 0; mt < 2; mt++)
#pragma unroll
        for (int ks = 0; ks < 2; ks++)
            aS[mt][ks] = *(const bf16x8*)(vq + (long long)(wrow + mt * 16 + cl) * Cz + ks * 32 + quad * 8);

    f32x4 Oacc[2][4] = {};
    float mrow[2][4], lrow[2][4];
#pragma unroll
    for (int mt = 0; mt < 2; mt++)
#pragma unroll
        for (int r = 0; r < 4; r++) { mrow[mt][r] = -3.0e38f; lrow[mt][r] = 0.f; }

    const u16* Ub = U + (long long)b * Tz * Cz + h * HDz;
    const u16* Vb = vT + ((long long)b * Cz + h * HDz) * Tz;

    for (int kt = 0; kt <= qi; kt++) {
        if (kt) __syncthreads();   // prev iteration's Vs/Ps reads complete
        const u16* Ug = Ub + (long long)kt * 128 * Cz;
#pragma unroll
        for (int i = 0; i < 4; i++) {
            int e = (i * 256 + tid) * 8;
            __builtin_amdgcn_global_load_lds(
                (const __attribute__((address_space(1))) uint32_t*)(Ug + (long long)(e >> 6) * Cz + (e & 63)),
                (__attribute__((address_space(3))) uint32_t*)(Us + e), 16, 0, 0);
        }
        const u16* Vg = Vb + kt * 128;
#pragma unroll
        for (int i = 0; i < 4; i++) {
            int e = (i * 256 + tid) * 8;
            __builtin_amdgcn_global_load_lds(
                (const __attribute__((address_space(1))) uint32_t*)(Vg + (long long)(e >> 7) * Tz + (e & 127)),
                (__attribute__((address_space(3))) uint32_t*)(Vs + e), 16, 0, 0);
        }
        __syncthreads();

        // S = vq . Uk^T  (wave tile 32 x 128)
        f32x4 S[2][8] = {};
#pragma unroll
        for (int ks = 0; ks < 2; ks++)
#pragma unroll
            for (int nt = 0; nt < 8; nt++) {
                bf16x8 bS = *(const bf16x8*)&Us[(nt * 16 + cl) * 64 + ks * 32 + quad * 8];
#pragma unroll
                for (int mt = 0; mt < 2; mt++)
                    S[mt][nt] = __builtin_amdgcn_mfma_f32_16x16x32_bf16(aS[mt][ks], bS, S[mt][nt], 0, 0, 0);
            }

        const bool diag = (kt == qi);
#pragma unroll
        for (int mt = 0; mt < 2; mt++)
#pragma unroll
            for (int nt = 0; nt < 8; nt++)
#pragma unroll
                for (int r = 0; r < 4; r++) {
                    int row = wrow + mt * 16 + quad * 4 + r;
                    int col = nt * 16 + cl;
                    float s = S[mt][nt][r] * 0.125f + bcs[kt * 128 + col];
                    if (diag && col > row) s = -3.0e38f;
                    S[mt][nt][r] = s;
                }

        // row max (across nt regs, then the 16 lanes of the quad group)
        float mnew[2][4], alpha[2][4];
#pragma unroll
        for (int mt = 0; mt < 2; mt++)
#pragma unroll
            for (int r = 0; r < 4; r++) {
                float m = S[mt][0][r];
#pragma unroll
                for (int nt = 1; nt < 8; nt++) m = fmaxf(m, S[mt][nt][r]);
#pragma unroll
                for (int d = 1; d < 16; d <<= 1) m = fmaxf(m, __shfl_xor(m, d));
                mnew[mt][r] = fmaxf(mrow[mt][r], m);
                alpha[mt][r] = __expf(mrow[mt][r] - mnew[mt][r]);
                mrow[mt][r] = mnew[mt][r];
            }

        // P = exp(S - m), write to LDS (A-layout source), accumulate row sums
        float psum[2][4] = {};
#pragma unroll
        for (int mt = 0; mt < 2; mt++)
#pragma unroll
            for (int nt = 0; nt < 8; nt++)
#pragma unroll
                for (int r = 0; r < 4; r++) {
                    float p = __expf(S[mt][nt][r] - mnew[mt][r]);
                    psum[mt][r] += p;
                    Ps[(wrow + mt * 16 + quad * 4 + r) * 136 + nt * 16 + cl] = f2bf(p);
                }
#pragma unroll
        for (int mt = 0; mt < 2; mt++)
#pragma unroll
            for (int r = 0; r < 4; r++) {
                float s = psum[mt][r];
#pragma unroll
                for (int d = 1; d < 16; d <<= 1) s += __shfl_xor(s, d);
                lrow[mt][r] = lrow[mt][r] * alpha[mt][r] + s;
#pragma unroll
                for (int nt2 = 0; nt2 < 4; nt2++)
                    Oacc[mt][nt2][r] *= alpha[mt][r];
            }

        __syncthreads();   // Ps visible

        // O += P . Vk   (K = 128)
#pragma unroll
        for (int ks = 0; ks < 4; ks++) {
            bf16x8 pA[2];
#pragma unroll
            for (int mt = 0; mt < 2; mt++)
                pA[mt] = *(const bf16x8*)&Ps[(wrow + mt * 16 + cl) * 136 + ks * 32 + quad * 8];
#pragma unroll
            for (int nt2 = 0; nt2 < 4; nt2++) {
                bf16x8 vB = *(const bf16x8*)&Vs[(nt2 * 16 + cl) * 128 + ks * 32 + quad * 8];
#pragma unroll
                for (int mt = 0; mt < 2; mt++)
                    Oacc[mt][nt2] = __builtin_amdgcn_mfma_f32_16x16x32_bf16(pA[mt], vB, Oacc[mt][nt2], 0, 0, 0);
            }
        }
    }

    // epilogue: O /= l, write y (in-place into v's own region)
    u16* yq = y + ((long long)b * Tz + q0) * Cz + h * HDz;
#pragma unroll
    for (int mt = 0; mt < 2; mt++)
#pragma unroll
        for (int r = 0; r < 4; r++) {
            float inv = 1.f / lrow[mt][r];
#pragma unroll
            for (int nt2 = 0; nt2 < 4; nt2++)
                yq[(long long)(wrow + mt * 16 + quad * 4 + r) * Cz + nt2 * 16 + cl] =
                    f2bf(Oacc[mt][nt2][r] * inv);
        }
}

// ---------------------------------------------------------------------------
extern "C" void kernel_launch(void* const* d_in, const int* in_sizes, int n_in,
                              void* d_out, int out_size, void* d_ws, size_t ws_size,
                              hipStream_t stream) {
    const float* x  = (const float*)d_in[0];
    const float* Wv = (const float*)d_in[1];
    const float* bv = (const float*)d_in[2];
    const float* Wl = (const float*)d_in[3];
    const float* Wc = (const float*)d_in[4];
    const float* bc = (const float*)d_in[5];
    const float* Wp = (const float*)d_in[6];
    const float* bp = (const float*)d_in[7];

    // ws (bf16 elems, ~59 MB): xb, Wvb, Wcb, Wpb, WlT, Wcl, vbf, vT, U
    u16* ws  = (u16*)d_ws;
    u16* xb  = ws;
    u16* Wvb = xb  + (size_t)Bz * Tz * Cz;
    u16* Wcb = Wvb + (size_t)Cz * Cz;
    u16* Wpb = Wcb + (size_t)Tz * Tz;
    u16* WlT = Wpb + (size_t)Cz * Cz;
    u16* Wcl = WlT + (size_t)Tz * Tz;
    u16* vbf = Wcl + (size_t)Tz * Tz;
    u16* vT  = vbf + (size_t)Bz * Tz * Cz;
    u16* U   = vT  + (size_t)Bz * Tz * Cz;

    const long long sTC = (long long)Tz * Cz;
    const long long sCT = (long long)Cz * Tz;

    // 0) one-time bf16 conversions
    cvt_f32_bf16<<<(Bz * Tz * Cz / 4 + 255) / 256, 256, 0, stream>>>(x, xb, Bz * Tz * Cz / 4);
    cvt_f32_bf16<<<(Cz * Cz / 4 + 255) / 256, 256, 0, stream>>>(Wv, Wvb, Cz * Cz / 4);
    cvt_f32_bf16<<<(Tz * Tz / 4 + 255) / 256, 256, 0, stream>>>(Wc, Wcb, Tz * Tz / 4);
    cvt_f32_bf16<<<(Cz * Cz / 4 + 255) / 256, 256, 0, stream>>>(Wp, Wpb, Cz * Cz / 4);
    // 1) WlT = Wl^T (fp32 -> bf16)
    transpose_to_bf16<true><<<dim3(32, 32, 1), dim3(32, 8), 0, stream>>>(Wl, WlT, Tz, Tz, 0, 0);
    // 2) Wcl = Wcb . WlT^T = Wc @ Wl
    gemm_bt<128, 128, 2, 2, false, false><<<dim3(8, 8, 1), 256, 0, stream>>>(
        Wcb, 0, Tz, WlT, 0, Tz, Wcl, 0, Tz, nullptr, Tz, 1.f);
    // 3) v = xb . Wvb^T + bv
    gemm_bt<128, 128, 2, 2, false, true><<<dim3(Cz / 128, (Bz * Tz) / 128, 1), 256, 0, stream>>>(
        xb, 0, Cz, Wvb, 0, Cz, vbf, 0, Cz, bv, Cz, 1.f);
    // 4) vT[b] = v[b]^T
    transpose_to_bf16<false><<<dim3(Cz / 32, Tz / 32, Bz), dim3(32, 8), 0, stream>>>(
        vbf, vT, Tz, Cz, sTC, sCT);
    // 5) U[b] = Wcl @ v[b]  (= Wcl . vT[b]^T), K=T
    gemm_bt<128, 128, 2, 2, false, false><<<dim3(Cz / 128, Tz / 128, Bz), 256, 0, stream>>>(
        Wcl, 0, Tz, vT, sCT, Tz, U, sTC, Cz, nullptr, Tz, 1.f);
    // 6) fused logits -> causal softmax -> P.V, y in-place into vbf
    flash_attn<<<dim3(Tz / 128, NHz, Bz), 256, 0, stream>>>(vbf, U, vT, bc, vbf);
    // 7) out = y . Wpb^T + bp  (fp32 out)
    gemm_bt<128, 128, 2, 2, true, true><<<dim3(Cz / 128, (Bz * Tz) / 128, 1), 256, 0, stream>>>(
        vbf, 0, Cz, Wpb, 0, Cz, (float*)d_out, 0, Cz, bp, Cz, 1.f);
}

// Round 8
// 338.734 us; speedup vs baseline: 5.3224x; 1.0016x over previous
//
#include <hip/hip_runtime.h>
#include <stdint.h>

#define Bz 8
#define Tz 1024
#define Cz 768
#define NHz 12
#define HDz 64

typedef unsigned short u16;
typedef __attribute__((ext_vector_type(8))) __bf16 bf16x8;
typedef __attribute__((ext_vector_type(4))) float f32x4;

__device__ __forceinline__ float bf2f(u16 b) {
    union { uint32_t u; float f; } c; c.u = ((uint32_t)b) << 16; return c.f;
}
__device__ __forceinline__ u16 f2bf(float f) {
    union { float f; uint32_t u; } c; c.f = f;
    uint32_t u = c.u;
    return (u16)((u + 0x7fffu + ((u >> 16) & 1u)) >> 16);
}

// ---------------------------------------------------------------------------
// fp32 -> bf16 elementwise convert (float4 / uint2 vectorized).
// ---------------------------------------------------------------------------
__global__ __launch_bounds__(256)
void cvt_f32_bf16(const float* __restrict__ in, u16* __restrict__ out, int n4) {
    int i = blockIdx.x * 256 + threadIdx.x;
    if (i < n4) {
        float4 v = ((const float4*)in)[i];
        union { u16 h[4]; uint2 u; } o;
        o.h[0] = f2bf(v.x); o.h[1] = f2bf(v.y); o.h[2] = f2bf(v.z); o.h[3] = f2bf(v.w);
        ((uint2*)out)[i] = o.u;
    }
}

// ---------------------------------------------------------------------------
// C = alpha * (A . B^T) [+ bias_col]   MFMA 16x16x32, all-bf16 operands.
// ---------------------------------------------------------------------------
template<int BM, int BN, int WM, int WN, bool OUTF32, bool HASBIAS>
__global__ __launch_bounds__(WM * WN * 64)
void gemm_bt(const u16* __restrict__ A, long long sAz, int lda,
             const u16* __restrict__ Bp, long long sBz, int ldb,
             void* __restrict__ Cp, long long sCz, int ldc,
             const float* __restrict__ bias, int K, float alpha) {
    constexpr int NT = WM * WN * 64;
    constexpr int BK = 32;
    constexpr int AI = (BM * BK) / (NT * 8);
    constexpr int BI = (BN * BK) / (NT * 8);
    static_assert(AI >= 1 && (BM * BK) % (NT * 8) == 0, "A staging");
    static_assert(BI >= 1 && (BN * BK) % (NT * 8) == 0, "B staging");
    static_assert(BM == WM * 64 && BN == WN * 64, "wave tiling");

    __shared__ alignas(16) u16 As[BM * BK];
    __shared__ alignas(16) u16 Bs[BN * BK];

    const int z = blockIdx.z;
    const u16* Ag = A + (long long)z * sAz;
    const u16* Bg = Bp + (long long)z * sBz;

    const int tid = threadIdx.x;
    const int lane = tid & 63;
    const int w = tid >> 6;
    const int wm = w / WN;
    const int wn = w % WN;
    const int rowBase = blockIdx.y * BM;
    const int colBase = blockIdx.x * BN;
    const int koff = (lane >> 4) * 8;
    const int frow = lane & 15;

    f32x4 acc[4][4] = {};

    for (int k0 = 0; k0 < K; k0 += BK) {
        __syncthreads();
#pragma unroll
        for (int i = 0; i < AI; i++) {
            int e = (i * NT + tid) * 8;
            const u16* g = Ag + (long long)(rowBase + (e >> 5)) * lda + k0 + (e & 31);
            __builtin_amdgcn_global_load_lds(
                (const __attribute__((address_space(1))) uint32_t*)g,
                (__attribute__((address_space(3))) uint32_t*)(As + e), 16, 0, 0);
        }
#pragma unroll
        for (int i = 0; i < BI; i++) {
            int e = (i * NT + tid) * 8;
            const u16* g = Bg + (long long)(colBase + (e >> 5)) * ldb + k0 + (e & 31);
            __builtin_amdgcn_global_load_lds(
                (const __attribute__((address_space(1))) uint32_t*)g,
                (__attribute__((address_space(3))) uint32_t*)(Bs + e), 16, 0, 0);
        }
        __syncthreads();

        bf16x8 af[4], bfr[4];
#pragma unroll
        for (int mt = 0; mt < 4; mt++)
            af[mt] = *(const bf16x8*)&As[(wm * 64 + mt * 16 + frow) * BK + koff];
#pragma unroll
        for (int nt = 0; nt < 4; nt++)
            bfr[nt] = *(const bf16x8*)&Bs[(wn * 64 + nt * 16 + frow) * BK + koff];
#pragma unroll
        for (int mt = 0; mt < 4; mt++)
#pragma unroll
            for (int nt = 0; nt < 4; nt++)
                acc[mt][nt] = __builtin_amdgcn_mfma_f32_16x16x32_bf16(
                    af[mt], bfr[nt], acc[mt][nt], 0, 0, 0);
    }

    const int r0 = rowBase + wm * 64;
    const int c0 = colBase + wn * 64;
    const int rl = (lane >> 4) * 4;
    const int cl = lane & 15;
#pragma unroll
    for (int mt = 0; mt < 4; mt++) {
#pragma unroll
        for (int nt = 0; nt < 4; nt++) {
#pragma unroll
            for (int r = 0; r < 4; r++) {
                int row = r0 + mt * 16 + rl + r;
                int col = c0 + nt * 16 + cl;
                float v = acc[mt][nt][r] * alpha;
                if (HASBIAS) v += bias[col];
                if (OUTF32)
                    ((float*)Cp)[(long long)z * sCz + (long long)row * ldc + col] = v;
                else
                    ((u16*)Cp)[(long long)z * sCz + (long long)row * ldc + col] = f2bf(v);
            }
        }
    }
}

// ---------------------------------------------------------------------------
// Transpose to bf16: in [rows,cols] (fp32 if INF32 else bf16) -> [cols,rows].
// ---------------------------------------------------------------------------
template<bool INF32>
__global__ __launch_bounds__(256)
void transpose_to_bf16(const void* __restrict__ in, u16* __restrict__ out,
                       int rows, int cols, long long sInZ, long long sOutZ) {
    __shared__ u16 tile[32][33];
    const int z = blockIdx.z;
    const int c0 = blockIdx.x * 32, r0 = blockIdx.y * 32;
    const int tx = threadIdx.x, ty = threadIdx.y;
#pragma unroll
    for (int i = 0; i < 32; i += 8) {
        long long off = (long long)z * sInZ + (long long)(r0 + ty + i) * cols + c0 + tx;
        tile[ty + i][tx] = INF32 ? f2bf(((const float*)in)[off]) : ((const u16*)in)[off];
    }
    __syncthreads();
#pragma unroll
    for (int i = 0; i < 32; i += 8)
        out[(long long)z * sOutZ + (long long)(c0 + ty + i) * rows + r0 + tx] = tile[tx][ty + i];
}

// ---------------------------------------------------------------------------
// Fused flash attention v2: Q-tile 64 (wave owns 16 q-rows), K-tile 128.
// grid (16, NH, B), blockIdx.x REVERSED so heaviest q-tiles dispatch first.
// LDS 53 KiB -> 3 blocks/CU (was 70 KiB -> 2). In-place y into v is
// race-free: each block reads exactly the v region it writes.
// ---------------------------------------------------------------------------
__global__ __launch_bounds__(256)
void flash_attn(const u16* __restrict__ v, const u16* __restrict__ U,
                const u16* __restrict__ vT, const float* __restrict__ bc,
                u16* __restrict__ y) {
    __shared__ alignas(16) u16 Us[128 * 64];    // keys x dims (packed)
    __shared__ alignas(16) u16 Vs[64 * 128];    // dims x keys (packed)
    __shared__ alignas(16) u16 Ps[64 * 136];    // q x keys, stride 136 (16B rows)
    __shared__ float bcs[Tz];

    const int qi = (gridDim.x - 1) - blockIdx.x;   // heavy tiles first
    const int h = blockIdx.y, b = blockIdx.z;
    const int tid = threadIdx.x, lane = tid & 63, w = tid >> 6;
    const int quad = lane >> 4, cl = lane & 15;
    const int q0 = qi * 64;
    const int wrow = w * 16;                        // wave's 16 q-rows

    for (int j = tid; j < Tz; j += 256) bcs[j] = bc[j];

    // resident A-fragments of vq (this block's own 64x64 slice)
    const u16* vq = v + ((long long)b * Tz + q0) * Cz + h * HDz;
    bf16x8 aS[2];
#pragma unroll
    for (int ks = 0; ks < 2; ks++)
        aS[ks] = *(const bf16x8*)(vq + (long long)(wrow + cl) * Cz + ks * 32 + quad * 8);

    f32x4 Oacc[4] = {};
    float mrow[4], lrow[4];
#pragma unroll
    for (int r = 0; r < 4; r++) { mrow[r] = -3.0e38f; lrow[r] = 0.f; }

    const u16* Ub = U + (long long)b * Tz * Cz + h * HDz;
    const u16* Vb = vT + ((long long)b * Cz + h * HDz) * Tz;

    const int kts = (qi + 2) >> 1;   // # of 128-wide k-tiles covering [0, q0+64)
    for (int kt = 0; kt < kts; kt++) {
        if (kt) __syncthreads();   // prev iteration's Vs/Ps reads complete
        const u16* Ug = Ub + (long long)kt * 128 * Cz;
#pragma unroll
        for (int i = 0; i < 4; i++) {
            int e = (i * 256 + tid) * 8;
            __builtin_amdgcn_global_load_lds(
                (const __attribute__((address_space(1))) uint32_t*)(Ug + (long long)(e >> 6) * Cz + (e & 63)),
                (__attribute__((address_space(3))) uint32_t*)(Us + e), 16, 0, 0);
        }
        const u16* Vg = Vb + kt * 128;
#pragma unroll
        for (int i = 0; i < 4; i++) {
            int e = (i * 256 + tid) * 8;
            __builtin_amdgcn_global_load_lds(
                (const __attribute__((address_space(1))) uint32_t*)(Vg + (long long)(e >> 7) * Tz + (e & 127)),
                (__attribute__((address_space(3))) uint32_t*)(Vs + e), 16, 0, 0);
        }
        __syncthreads();

        // S = vq . Uk^T  (wave tile 16 x 128)
        f32x4 S[8] = {};
#pragma unroll
        for (int ks = 0; ks < 2; ks++)
#pragma unroll
            for (int nt = 0; nt < 8; nt++) {
                bf16x8 bS = *(const bf16x8*)&Us[(nt * 16 + cl) * 64 + ks * 32 + quad * 8];
                S[nt] = __builtin_amdgcn_mfma_f32_16x16x32_bf16(aS[ks], bS, S[nt], 0, 0, 0);
            }

        const bool last = (kt == kts - 1);
#pragma unroll
        for (int nt = 0; nt < 8; nt++)
#pragma unroll
            for (int r = 0; r < 4; r++) {
                int rowg = q0 + wrow + quad * 4 + r;
                int colg = kt * 128 + nt * 16 + cl;
                float s = S[nt][r] * 0.125f + bcs[colg];
                if (last && colg > rowg) s = -3.0e38f;
                S[nt][r] = s;
            }

        // row max (regs, then across the 16 lanes of the quad group)
        float mnew[4], alpha[4];
#pragma unroll
        for (int r = 0; r < 4; r++) {
            float m = S[0][r];
#pragma unroll
            for (int nt = 1; nt < 8; nt++) m = fmaxf(m, S[nt][r]);
#pragma unroll
            for (int d = 1; d < 16; d <<= 1) m = fmaxf(m, __shfl_xor(m, d));
            mnew[r] = fmaxf(mrow[r], m);
            alpha[r] = __expf(mrow[r] - mnew[r]);
            mrow[r] = mnew[r];
        }

        // P = exp(S - m) -> LDS (A-layout source), accumulate row sums
        float psum[4] = {};
#pragma unroll
        for (int nt = 0; nt < 8; nt++)
#pragma unroll
            for (int r = 0; r < 4; r++) {
                float p = __expf(S[nt][r] - mnew[r]);
                psum[r] += p;
                Ps[(wrow + quad * 4 + r) * 136 + nt * 16 + cl] = f2bf(p);
            }
#pragma unroll
        for (int r = 0; r < 4; r++) {
            float s = psum[r];
#pragma unroll
            for (int d = 1; d < 16; d <<= 1) s += __shfl_xor(s, d);
            lrow[r] = lrow[r] * alpha[r] + s;
#pragma unroll
            for (int nt2 = 0; nt2 < 4; nt2++)
                Oacc[nt2][r] *= alpha[r];
        }

        __syncthreads();   // Ps visible

        // O += P . Vk   (K = 128)
#pragma unroll
        for (int ks = 0; ks < 4; ks++) {
            bf16x8 pA = *(const bf16x8*)&Ps[(wrow + cl) * 136 + ks * 32 + quad * 8];
#pragma unroll
            for (int nt2 = 0; nt2 < 4; nt2++) {
                bf16x8 vB = *(const bf16x8*)&Vs[(nt2 * 16 + cl) * 128 + ks * 32 + quad * 8];
                Oacc[nt2] = __builtin_amdgcn_mfma_f32_16x16x32_bf16(pA, vB, Oacc[nt2], 0, 0, 0);
            }
        }
    }

    // epilogue: O /= l, write y (in-place into v's own region)
    u16* yq = y + ((long long)b * Tz + q0) * Cz + h * HDz;
#pragma unroll
    for (int r = 0; r < 4; r++) {
        float inv = 1.f / lrow[r];
#pragma unroll
        for (int nt2 = 0; nt2 < 4; nt2++)
            yq[(long long)(wrow + quad * 4 + r) * Cz + nt2 * 16 + cl] =
                f2bf(Oacc[nt2][r] * inv);
    }
}

// ---------------------------------------------------------------------------
extern "C" void kernel_launch(void* const* d_in, const int* in_sizes, int n_in,
                              void* d_out, int out_size, void* d_ws, size_t ws_size,
                              hipStream_t stream) {
    const float* x  = (const float*)d_in[0];
    const float* Wv = (const float*)d_in[1];
    const float* bv = (const float*)d_in[2];
    const float* Wl = (const float*)d_in[3];
    const float* Wc = (const float*)d_in[4];
    const float* bc = (const float*)d_in[5];
    const float* Wp = (const float*)d_in[6];
    const float* bp = (const float*)d_in[7];

    // ws (bf16 elems, ~59 MB): xb, Wvb, Wcb, Wpb, WlT, Wcl, vbf, vT, U
    u16* ws  = (u16*)d_ws;
    u16* xb  = ws;
    u16* Wvb = xb  + (size_t)Bz * Tz * Cz;
    u16* Wcb = Wvb + (size_t)Cz * Cz;
    u16* Wpb = Wcb + (size_t)Tz * Tz;
    u16* WlT = Wpb + (size_t)Cz * Cz;
    u16* Wcl = WlT + (size_t)Tz * Tz;
    u16* vbf = Wcl + (size_t)Tz * Tz;
    u16* vT  = vbf + (size_t)Bz * Tz * Cz;
    u16* U   = vT  + (size_t)Bz * Tz * Cz;

    const long long sTC = (long long)Tz * Cz;
    const long long sCT = (long long)Cz * Tz;

    // 0) one-time bf16 conversions
    cvt_f32_bf16<<<(Bz * Tz * Cz / 4 + 255) / 256, 256, 0, stream>>>(x, xb, Bz * Tz * Cz / 4);
    cvt_f32_bf16<<<(Cz * Cz / 4 + 255) / 256, 256, 0, stream>>>(Wv, Wvb, Cz * Cz / 4);
    cvt_f32_bf16<<<(Tz * Tz / 4 + 255) / 256, 256, 0, stream>>>(Wc, Wcb, Tz * Tz / 4);
    cvt_f32_bf16<<<(Cz * Cz / 4 + 255) / 256, 256, 0, stream>>>(Wp, Wpb, Cz * Cz / 4);
    // 1) WlT = Wl^T (fp32 -> bf16)
    transpose_to_bf16<true><<<dim3(32, 32, 1), dim3(32, 8), 0, stream>>>(Wl, WlT, Tz, Tz, 0, 0);
    // 2) Wcl = Wcb . WlT^T = Wc @ Wl
    gemm_bt<128, 128, 2, 2, false, false><<<dim3(8, 8, 1), 256, 0, stream>>>(
        Wcb, 0, Tz, WlT, 0, Tz, Wcl, 0, Tz, nullptr, Tz, 1.f);
    // 3) v = xb . Wvb^T + bv
    gemm_bt<128, 128, 2, 2, false, true><<<dim3(Cz / 128, (Bz * Tz) / 128, 1), 256, 0, stream>>>(
        xb, 0, Cz, Wvb, 0, Cz, vbf, 0, Cz, bv, Cz, 1.f);
    // 4) vT[b] = v[b]^T
    transpose_to_bf16<false><<<dim3(Cz / 32, Tz / 32, Bz), dim3(32, 8), 0, stream>>>(
        vbf, vT, Tz, Cz, sTC, sCT);
    // 5) U[b] = Wcl @ v[b]  (= Wcl . vT[b]^T), K=T
    gemm_bt<128, 128, 2, 2, false, false><<<dim3(Cz / 128, Tz / 128, Bz), 256, 0, stream>>>(
        Wcl, 0, Tz, vT, sCT, Tz, U, sTC, Cz, nullptr, Tz, 1.f);
    // 6) fused logits -> causal softmax -> P.V, y in-place into vbf
    flash_attn<<<dim3(Tz / 64, NHz, Bz), 256, 0, stream>>>(vbf, U, vT, bc, vbf);
    // 7) out = y . Wpb^T + bp  (fp32 out)
    gemm_bt<128, 128, 2, 2, true, true><<<dim3(Cz / 128, (Bz * Tz) / 128, 1), 256, 0, stream>>>(
        vbf, 0, Cz, Wpb, 0, Cz, (float*)d_out, 0, Cz, bp, Cz, 1.f);
}

// Round 9
// 261.551 us; speedup vs baseline: 6.8931x; 1.2951x over previous
//
#include <hip/hip_runtime.h>
#include <stdint.h>

#define Bz 8
#define Tz 1024
#define Cz 768
#define NHz 12
#define HDz 64

typedef unsigned short u16;
typedef __attribute__((ext_vector_type(8))) __bf16 bf16x8;
typedef __attribute__((ext_vector_type(4))) float f32x4;

__device__ __forceinline__ float bf2f(u16 b) {
    union { uint32_t u; float f; } c; c.u = ((uint32_t)b) << 16; return c.f;
}
__device__ __forceinline__ u16 f2bf(float f) {
    union { float f; uint32_t u; } c; c.f = f;
    uint32_t u = c.u;
    return (u16)((u + 0x7fffu + ((u >> 16) & 1u)) >> 16);
}

// ---------------------------------------------------------------------------
// fp32 -> bf16 elementwise convert (float4 / uint2 vectorized).
// ---------------------------------------------------------------------------
__global__ __launch_bounds__(256)
void cvt_f32_bf16(const float* __restrict__ in, u16* __restrict__ out, int n4) {
    int i = blockIdx.x * 256 + threadIdx.x;
    if (i < n4) {
        float4 v = ((const float4*)in)[i];
        union { u16 h[4]; uint2 u; } o;
        o.h[0] = f2bf(v.x); o.h[1] = f2bf(v.y); o.h[2] = f2bf(v.z); o.h[3] = f2bf(v.w);
        ((uint2*)out)[i] = o.u;
    }
}

// ---------------------------------------------------------------------------
// C = alpha * (A . B^T) [+ bias_col]   MFMA 16x16x32, all-bf16 operands.
// ---------------------------------------------------------------------------
template<int BM, int BN, int WM, int WN, bool OUTF32, bool HASBIAS>
__global__ __launch_bounds__(WM * WN * 64)
void gemm_bt(const u16* __restrict__ A, long long sAz, int lda,
             const u16* __restrict__ Bp, long long sBz, int ldb,
             void* __restrict__ Cp, long long sCz, int ldc,
             const float* __restrict__ bias, int K, float alpha) {
    constexpr int NT = WM * WN * 64;
    constexpr int BK = 32;
    constexpr int AI = (BM * BK) / (NT * 8);
    constexpr int BI = (BN * BK) / (NT * 8);
    static_assert(AI >= 1 && (BM * BK) % (NT * 8) == 0, "A staging");
    static_assert(BI >= 1 && (BN * BK) % (NT * 8) == 0, "B staging");
    static_assert(BM == WM * 64 && BN == WN * 64, "wave tiling");

    __shared__ alignas(16) u16 As[BM * BK];
    __shared__ alignas(16) u16 Bs[BN * BK];

    const int z = blockIdx.z;
    const u16* Ag = A + (long long)z * sAz;
    const u16* Bg = Bp + (long long)z * sBz;

    const int tid = threadIdx.x;
    const int lane = tid & 63;
    const int w = tid >> 6;
    const int wm = w / WN;
    const int wn = w % WN;
    const int rowBase = blockIdx.y * BM;
    const int colBase = blockIdx.x * BN;
    const int koff = (lane >> 4) * 8;
    const int frow = lane & 15;

    f32x4 acc[4][4] = {};

    for (int k0 = 0; k0 < K; k0 += BK) {
        __syncthreads();
#pragma unroll
        for (int i = 0; i < AI; i++) {
            int e = (i * NT + tid) * 8;
            const u16* g = Ag + (long long)(rowBase + (e >> 5)) * lda + k0 + (e & 31);
            __builtin_amdgcn_global_load_lds(
                (const __attribute__((address_space(1))) uint32_t*)g,
                (__attribute__((address_space(3))) uint32_t*)(As + e), 16, 0, 0);
        }
#pragma unroll
        for (int i = 0; i < BI; i++) {
            int e = (i * NT + tid) * 8;
            const u16* g = Bg + (long long)(colBase + (e >> 5)) * ldb + k0 + (e & 31);
            __builtin_amdgcn_global_load_lds(
                (const __attribute__((address_space(1))) uint32_t*)g,
                (__attribute__((address_space(3))) uint32_t*)(Bs + e), 16, 0, 0);
        }
        __syncthreads();

        bf16x8 af[4], bfr[4];
#pragma unroll
        for (int mt = 0; mt < 4; mt++)
            af[mt] = *(const bf16x8*)&As[(wm * 64 + mt * 16 + frow) * BK + koff];
#pragma unroll
        for (int nt = 0; nt < 4; nt++)
            bfr[nt] = *(const bf16x8*)&Bs[(wn * 64 + nt * 16 + frow) * BK + koff];
#pragma unroll
        for (int mt = 0; mt < 4; mt++)
#pragma unroll
            for (int nt = 0; nt < 4; nt++)
                acc[mt][nt] = __builtin_amdgcn_mfma_f32_16x16x32_bf16(
                    af[mt], bfr[nt], acc[mt][nt], 0, 0, 0);
    }

    const int r0 = rowBase + wm * 64;
    const int c0 = colBase + wn * 64;
    const int rl = (lane >> 4) * 4;
    const int cl = lane & 15;
#pragma unroll
    for (int mt = 0; mt < 4; mt++) {
#pragma unroll
        for (int nt = 0; nt < 4; nt++) {
#pragma unroll
            for (int r = 0; r < 4; r++) {
                int row = r0 + mt * 16 + rl + r;
                int col = c0 + nt * 16 + cl;
                float v = acc[mt][nt][r] * alpha;
                if (HASBIAS) v += bias[col];
                if (OUTF32)
                    ((float*)Cp)[(long long)z * sCz + (long long)row * ldc + col] = v;
                else
                    ((u16*)Cp)[(long long)z * sCz + (long long)row * ldc + col] = f2bf(v);
            }
        }
    }
}

// ---------------------------------------------------------------------------
// Transpose to bf16: in [rows,cols] (fp32 if INF32 else bf16) -> [cols,rows].
// ---------------------------------------------------------------------------
template<bool INF32>
__global__ __launch_bounds__(256)
void transpose_to_bf16(const void* __restrict__ in, u16* __restrict__ out,
                       int rows, int cols, long long sInZ, long long sOutZ) {
    __shared__ u16 tile[32][33];
    const int z = blockIdx.z;
    const int c0 = blockIdx.x * 32, r0 = blockIdx.y * 32;
    const int tx = threadIdx.x, ty = threadIdx.y;
#pragma unroll
    for (int i = 0; i < 32; i += 8) {
        long long off = (long long)z * sInZ + (long long)(r0 + ty + i) * cols + c0 + tx;
        tile[ty + i][tx] = INF32 ? f2bf(((const float*)in)[off]) : ((const u16*)in)[off];
    }
    __syncthreads();
#pragma unroll
    for (int i = 0; i < 32; i += 8)
        out[(long long)z * sOutZ + (long long)(c0 + ty + i) * rows + r0 + tx] = tile[tx][ty + i];
}

// ---------------------------------------------------------------------------
// Fused flash attention v3.
//  - Q-tile 64 (wave owns 16 q-rows), K-tile 128.
//  - Flat grid 1536 with XCD-aware remap: all 16 q-blocks of a (b,h) column
//    share blockIdx%8 (-> same XCD L2; 12 cols x 256KB = 3MB < 4MB L2),
//    heavy q-tiles dispatch first.
//  - Us/Vs XOR-chunk-swizzled on the GLOBAL source side of global_load_lds
//    (LDS side must stay lane-linear); readers XOR back. Kills the 16-way
//    bank conflicts of the power-of-2 row strides -> 2-way (free).
//  - 2 barriers/iter: Ps rows are wave-private, pre-PV barrier removed.
// In-place y into v is race-free: block reads exactly the region it writes.
// ---------------------------------------------------------------------------
__global__ __launch_bounds__(256)
void flash_attn(const u16* __restrict__ v, const u16* __restrict__ U,
                const u16* __restrict__ vT, const float* __restrict__ bc,
                u16* __restrict__ y) {
    __shared__ alignas(16) u16 Us[128 * 64];    // [key][chunk^key&7] (swizzled)
    __shared__ alignas(16) u16 Vs[64 * 128];    // [dim][chunk^dim&15] (swizzled)
    __shared__ alignas(16) u16 Ps[64 * 136];    // q x keys, stride 136
    __shared__ float bcs[Tz];

    // grid remap: xcd-affine columns, heavy qi first
    const int bi = blockIdx.x;
    const int xcd = bi & 7;
    const int slot = bi >> 3;                   // 0..191
    const int col = (slot % 12) * 8 + xcd;      // 0..95, col%8 == xcd
    const int qi = 15 - slot / 12;              // heavy tiles first
    const int b = col / NHz, h = col % NHz;

    const int tid = threadIdx.x, lane = tid & 63, w = tid >> 6;
    const int quad = lane >> 4, cl = lane & 15;
    const int q0 = qi * 64;
    const int wrow = w * 16;                    // wave's 16 q-rows

    for (int j = tid; j < Tz; j += 256) bcs[j] = bc[j];

    // resident A-fragments of vq (this block's own 64x64 slice)
    const u16* vq = v + ((long long)b * Tz + q0) * Cz + h * HDz;
    bf16x8 aS[2];
#pragma unroll
    for (int ks = 0; ks < 2; ks++)
        aS[ks] = *(const bf16x8*)(vq + (long long)(wrow + cl) * Cz + ks * 32 + quad * 8);

    f32x4 Oacc[4] = {};
    float mrow[4], lrow[4];
#pragma unroll
    for (int r = 0; r < 4; r++) { mrow[r] = -3.0e38f; lrow[r] = 0.f; }

    const u16* Ub = U + (long long)b * Tz * Cz + h * HDz;
    const u16* Vb = vT + ((long long)b * Cz + h * HDz) * Tz;

    const int kts = (qi + 2) >> 1;   // # of 128-wide k-tiles covering [0, q0+64)
    for (int kt = 0; kt < kts; kt++) {
        if (kt) __syncthreads();   // prev iter's Us (S) / Vs (PV) reads complete
        const u16* Ug = Ub + (long long)kt * 128 * Cz;
#pragma unroll
        for (int i = 0; i < 4; i++) {
            int e = (i * 256 + tid) * 8;
            int key = e >> 6;
            int ch = ((e & 63) >> 3) ^ (key & 7);   // global-side swizzle
            __builtin_amdgcn_global_load_lds(
                (const __attribute__((address_space(1))) uint32_t*)(Ug + (long long)key * Cz + ch * 8),
                (__attribute__((address_space(3))) uint32_t*)(Us + e), 16, 0, 0);
        }
        const u16* Vg = Vb + kt * 128;
#pragma unroll
        for (int i = 0; i < 4; i++) {
            int e = (i * 256 + tid) * 8;
            int dim = e >> 7;
            int ch = ((e & 127) >> 3) ^ (dim & 15);  // global-side swizzle
            __builtin_amdgcn_global_load_lds(
                (const __attribute__((address_space(1))) uint32_t*)(Vg + (long long)dim * Tz + ch * 8),
                (__attribute__((address_space(3))) uint32_t*)(Vs + e), 16, 0, 0);
        }
        __syncthreads();

        // S = vq . Uk^T  (wave tile 16 x 128)
        f32x4 S[8] = {};
#pragma unroll
        for (int ks = 0; ks < 2; ks++)
#pragma unroll
            for (int nt = 0; nt < 8; nt++) {
                int key = nt * 16 + cl;
                bf16x8 bS = *(const bf16x8*)&Us[key * 64 + (((ks * 4 + quad) ^ (key & 7)) * 8)];
                S[nt] = __builtin_amdgcn_mfma_f32_16x16x32_bf16(aS[ks], bS, S[nt], 0, 0, 0);
            }

        const bool last = (kt == kts - 1);
#pragma unroll
        for (int nt = 0; nt < 8; nt++)
#pragma unroll
            for (int r = 0; r < 4; r++) {
                int rowg = q0 + wrow + quad * 4 + r;
                int colg = kt * 128 + nt * 16 + cl;
                float s = S[nt][r] * 0.125f + bcs[colg];
                if (last && colg > rowg) s = -3.0e38f;
                S[nt][r] = s;
            }

        // row max (regs, then across the 16 lanes of the quad group)
        float mnew[4], alpha[4];
#pragma unroll
        for (int r = 0; r < 4; r++) {
            float m = S[0][r];
#pragma unroll
            for (int nt = 1; nt < 8; nt++) m = fmaxf(m, S[nt][r]);
#pragma unroll
            for (int d = 1; d < 16; d <<= 1) m = fmaxf(m, __shfl_xor(m, d));
            mnew[r] = fmaxf(mrow[r], m);
            alpha[r] = __expf(mrow[r] - mnew[r]);
            mrow[r] = mnew[r];
        }

        // P = exp(S - m) -> LDS (wave-private rows), accumulate row sums
        float psum[4] = {};
#pragma unroll
        for (int nt = 0; nt < 8; nt++)
#pragma unroll
            for (int r = 0; r < 4; r++) {
                float p = __expf(S[nt][r] - mnew[r]);
                psum[r] += p;
                Ps[(wrow + quad * 4 + r) * 136 + nt * 16 + cl] = f2bf(p);
            }
#pragma unroll
        for (int r = 0; r < 4; r++) {
            float s = psum[r];
#pragma unroll
            for (int d = 1; d < 16; d <<= 1) s += __shfl_xor(s, d);
            lrow[r] = lrow[r] * alpha[r] + s;
#pragma unroll
            for (int nt2 = 0; nt2 < 4; nt2++)
                Oacc[nt2][r] *= alpha[r];
        }

        // no barrier: Ps rows are wave-private; same-wave DS ordering suffices

        // O += P . Vk   (K = 128)
#pragma unroll
        for (int ks = 0; ks < 4; ks++) {
            bf16x8 pA = *(const bf16x8*)&Ps[(wrow + cl) * 136 + ks * 32 + quad * 8];
#pragma unroll
            for (int nt2 = 0; nt2 < 4; nt2++) {
                int dim = nt2 * 16 + cl;
                bf16x8 vB = *(const bf16x8*)&Vs[dim * 128 + (((ks * 4 + quad) ^ cl) * 8)];
                Oacc[nt2] = __builtin_amdgcn_mfma_f32_16x16x32_bf16(pA, vB, Oacc[nt2], 0, 0, 0);
            }
        }
    }

    // epilogue: O /= l, write y (in-place into v's own region)
    u16* yq = y + ((long long)b * Tz + q0) * Cz + h * HDz;
#pragma unroll
    for (int r = 0; r < 4; r++) {
        float inv = 1.f / lrow[r];
#pragma unroll
        for (int nt2 = 0; nt2 < 4; nt2++)
            yq[(long long)(wrow + quad * 4 + r) * Cz + nt2 * 16 + cl] =
                f2bf(Oacc[nt2][r] * inv);
    }
}

// ---------------------------------------------------------------------------
extern "C" void kernel_launch(void* const* d_in, const int* in_sizes, int n_in,
                              void* d_out, int out_size, void* d_ws, size_t ws_size,
                              hipStream_t stream) {
    const float* x  = (const float*)d_in[0];
    const float* Wv = (const float*)d_in[1];
    const float* bv = (const float*)d_in[2];
    const float* Wl = (const float*)d_in[3];
    const float* Wc = (const float*)d_in[4];
    const float* bc = (const float*)d_in[5];
    const float* Wp = (const float*)d_in[6];
    const float* bp = (const float*)d_in[7];

    // ws (bf16 elems, ~59 MB): xb, Wvb, Wcb, Wpb, WlT, Wcl, vbf, vT, U
    u16* ws  = (u16*)d_ws;
    u16* xb  = ws;
    u16* Wvb = xb  + (size_t)Bz * Tz * Cz;
    u16* Wcb = Wvb + (size_t)Cz * Cz;
    u16* Wpb = Wcb + (size_t)Tz * Tz;
    u16* WlT = Wpb + (size_t)Cz * Cz;
    u16* Wcl = WlT + (size_t)Tz * Tz;
    u16* vbf = Wcl + (size_t)Tz * Tz;
    u16* vT  = vbf + (size_t)Bz * Tz * Cz;
    u16* U   = vT  + (size_t)Bz * Tz * Cz;

    const long long sTC = (long long)Tz * Cz;
    const long long sCT = (long long)Cz * Tz;

    // 0) one-time bf16 conversions
    cvt_f32_bf16<<<(Bz * Tz * Cz / 4 + 255) / 256, 256, 0, stream>>>(x, xb, Bz * Tz * Cz / 4);
    cvt_f32_bf16<<<(Cz * Cz / 4 + 255) / 256, 256, 0, stream>>>(Wv, Wvb, Cz * Cz / 4);
    cvt_f32_bf16<<<(Tz * Tz / 4 + 255) / 256, 256, 0, stream>>>(Wc, Wcb, Tz * Tz / 4);
    cvt_f32_bf16<<<(Cz * Cz / 4 + 255) / 256, 256, 0, stream>>>(Wp, Wpb, Cz * Cz / 4);
    // 1) WlT = Wl^T (fp32 -> bf16)
    transpose_to_bf16<true><<<dim3(32, 32, 1), dim3(32, 8), 0, stream>>>(Wl, WlT, Tz, Tz, 0, 0);
    // 2) Wcl = Wcb . WlT^T = Wc @ Wl
    gemm_bt<128, 128, 2, 2, false, false><<<dim3(8, 8, 1), 256, 0, stream>>>(
        Wcb, 0, Tz, WlT, 0, Tz, Wcl, 0, Tz, nullptr, Tz, 1.f);
    // 3) v = xb . Wvb^T + bv
    gemm_bt<128, 128, 2, 2, false, true><<<dim3(Cz / 128, (Bz * Tz) / 128, 1), 256, 0, stream>>>(
        xb, 0, Cz, Wvb, 0, Cz, vbf, 0, Cz, bv, Cz, 1.f);
    // 4) vT[b] = v[b]^T
    transpose_to_bf16<false><<<dim3(Cz / 32, Tz / 32, Bz), dim3(32, 8), 0, stream>>>(
        vbf, vT, Tz, Cz, sTC, sCT);
    // 5) U[b] = Wcl @ v[b]  (= Wcl . vT[b]^T), K=T
    gemm_bt<128, 128, 2, 2, false, false><<<dim3(Cz / 128, Tz / 128, Bz), 256, 0, stream>>>(
        Wcl, 0, Tz, vT, sCT, Tz, U, sTC, Cz, nullptr, Tz, 1.f);
    // 6) fused logits -> causal softmax -> P.V, y in-place into vbf
    flash_attn<<<dim3((Tz / 64) * NHz * Bz, 1, 1), 256, 0, stream>>>(vbf, U, vT, bc, vbf);
    // 7) out = y . Wpb^T + bp  (fp32 out)
    gemm_bt<128, 128, 2, 2, true, true><<<dim3(Cz / 128, (Bz * Tz) / 128, 1), 256, 0, stream>>>(
        vbf, 0, Cz, Wpb, 0, Cz, (float*)d_out, 0, Cz, bp, Cz, 1.f);
}